// Round 11
// baseline (228.293 us; speedup 1.0000x reference)
//
#include <hip/hip_runtime.h>
#include <stdint.h>

#define TAGS 10
#define START_TAG 8
#define STOP_TAG 9
#define NEGV (-10000.0f)
#define BIGNEG (-1.0e9f)

// DPP within 16-lane rows: ROW_ROR:r = 0x120+r, QUAD_PERM[1,0,3,2] = 0xB1.
#define DPP_I(x, ctrl) __builtin_amdgcn_update_dpp(0, (x), (ctrl), 0xF, 0xF, true)
// ds_swizzle BitMode XOR-r within 32-lane halves.
#define SWZ_I(x, r) __builtin_amdgcn_ds_swizzle((x), (((r) << 10) | 0x1F))

__device__ __forceinline__ float maxf3(float a, float b, float c) {
    return fmaxf(fmaxf(a, b), c);   // folds to v_max3_f32
}

// Inline-asm feat loads: structurally pinned (regalloc cannot sink them).
#define GLOADI(dst, base, OFF) \
    asm volatile("global_load_dword %0, %1, off offset:" #OFF \
                 : "=v"(dst) : "v"(base))
#define GLOAD8(BUF, BASE) { \
    const float* gb_ = (BASE); \
    GLOADI(BUF[0], gb_, 0);   GLOADI(BUF[1], gb_, 40); \
    GLOADI(BUF[2], gb_, 80);  GLOADI(BUF[3], gb_, 120); \
    GLOADI(BUF[4], gb_, 160); GLOADI(BUF[5], gb_, 200); \
    GLOADI(BUF[6], gb_, 240); GLOADI(BUF[7], gb_, 280); }
#define WAITP { asm volatile("s_waitcnt vmcnt(16)" ::: "memory"); \
                __builtin_amdgcn_sched_barrier(0); }
#define PINFENCE __builtin_amdgcn_sched_barrier(0);

// ===========================================================================
// K1: split forward (verbatim R10 — 78.6 us measured).
// ===========================================================================
__global__ __launch_bounds__(64, 1) void crf_split_fwd(
    const float* __restrict__ feats,
    const int*   __restrict__ lengths,
    const float* __restrict__ trans,
    uint8_t*     __restrict__ bpA,
    uint8_t*     __restrict__ bpB,
    float*       __restrict__ fvAo,
    float*       __restrict__ gws,
    int B, int T, int H, int ABLK)
{
    const int lane = threadIdx.x & 63;

    if ((int)blockIdx.x < ABLK) {
        // ---------------- half A ----------------
        const int grp  = lane >> 4;
        const int n    = lane & 15;
        const int m    = n & 7;
        const bool odd = (n & 1);
        const int b4   = blockIdx.x * 4;
        const int b    = min(b4 + grp, B - 1);

        const int len  = lengths[b];
        const int lenA = min(len, H);
        const int l0 = lengths[min(b4 + 0, B - 1)];
        const int l1 = lengths[min(b4 + 1, B - 1)];
        const int l2 = lengths[min(b4 + 2, B - 1)];
        const int l3 = lengths[min(b4 + 3, B - 1)];
        const int HA = min(max(max(l0, l1), max(l2, l3)), H);
        const int blocksA = (H + 6) >> 3;

        int srcv[8];
        srcv[0] = n;
        srcv[1] = DPP_I(n, 0x121);  srcv[2] = DPP_I(n, 0x122);
        srcv[3] = DPP_I(n, 0x123);  srcv[4] = DPP_I(n, 0x124);
        srcv[5] = DPP_I(n, 0x125);  srcv[6] = DPP_I(n, 0x126);
        srcv[7] = DPP_I(n, 0x127);

        float trowR[8];
        int   rsrc[8];
#pragma unroll
        for (int r = 0; r < 8; ++r) {
            const int sq = srcv[r] & 7;
            trowR[r] = trans[m * TAGS + sq];
            rsrc[r]  = sq ^ 7;
        }

        const float* fb = feats + (size_t)b * T * TAGS + m;
        uint8_t* bpa_l = bpA + (size_t)b * blocksA * 32 + ((n >> 1) & 3) * 8;
        const bool stl = (n < 8) && !odd;

        float fv = trans[m * TAGS + START_TAG] + fb[0];

#define KLEAF_A(r, ctrl) { \
        int rot_ = DPP_I(__float_as_int(fv), (ctrl)); \
        float lv_ = __int_as_float(rot_) + trowR[r]; \
        k##r = __int_as_float((__float_as_int(lv_) & ~7) | rsrc[r]); }

#define STEP_A(TI, FEAT, ACCST) { \
        const int t_ = (TI); \
        float k0, k1, k2, k3, k4, k5, k6, k7; \
        { float lv_ = fv + trowR[0]; \
          k0 = __int_as_float((__float_as_int(lv_) & ~7) | rsrc[0]); } \
        KLEAF_A(1, 0x121) KLEAF_A(2, 0x122) KLEAF_A(3, 0x123) \
        KLEAF_A(4, 0x124) KLEAF_A(5, 0x125) KLEAF_A(6, 0x126) \
        KLEAF_A(7, 0x127) \
        const float p1_ = maxf3(k0, k1, k2); \
        const float p2_ = maxf3(k3, k4, k5); \
        const float p3_ = maxf3(k6, k7, p1_); \
        const float mm_ = fmaxf(p2_, p3_); \
        const int idx_  = (__float_as_int(mm_) & 7) ^ 7; \
        const int pidx_ = DPP_I(idx_, 0xB1); \
        const uint32_t byte_ = (uint32_t)(odd ? (pidx_ | (idx_ << 4)) \
                                              : (idx_ | (pidx_ << 4))); \
        ACCST; \
        const float fvn_ = mm_ + (FEAT); \
        fv = (t_ < lenA) ? fvn_ : fv; }

#define PH_A(USE, LD, T0) { \
        GLOAD8(LD, fb + (size_t)min((T0) + 16, T - 8) * TAGS); \
        WAITP \
        uint32_t accl, acch; \
        STEP_A((T0) + 0, USE[0], accl = byte_) \
        STEP_A((T0) + 1, USE[1], accl |= byte_ << 8) \
        STEP_A((T0) + 2, USE[2], accl |= byte_ << 16) \
        STEP_A((T0) + 3, USE[3], accl |= byte_ << 24) \
        STEP_A((T0) + 4, USE[4], acch = byte_) \
        STEP_A((T0) + 5, USE[5], acch |= byte_ << 8) \
        STEP_A((T0) + 6, USE[6], acch |= byte_ << 16) \
        STEP_A((T0) + 7, USE[7], acch |= byte_ << 24) \
        if ((T0) < H) { \
            if (stl) *(uint2*)(bpa_l + (size_t)(((T0) - 1) >> 3) * 32) \
                         = make_uint2(accl, acch); } }

        PINFENCE
        float xb[8], yb[8], zb[8];
        GLOAD8(xb, fb + (size_t)1 * TAGS);
        GLOAD8(yb, fb + (size_t)min(9, T - 8) * TAGS);

        for (int t0 = 1; t0 < HA; t0 += 24) {
            PH_A(xb, zb, t0)
            PH_A(yb, xb, t0 + 8)
            PH_A(zb, yb, t0 + 16)
        }
#undef KLEAF_A
#undef STEP_A
#undef PH_A

        if (n < 8)
            fvAo[(size_t)b * 8 + m] = fv;
    } else {
        // ---------------- half B ----------------
        const int s = blockIdx.x - ABLK;
        if (s >= B) return;
        const int len = lengths[s];
        if (len <= H) return;

        const int p    = lane >> 3;
        const int n    = lane & 7;
        const bool odd = (n & 1);
        const int blocksB = (T - H + 7) >> 3;

        float trowR[8];
        int   rsrc[8];
#pragma unroll
        for (int r = 0; r < 8; ++r) {
            const int q = n ^ r;
            trowR[r] = trans[n * TAGS + q];
            rsrc[r]  = q ^ 7;
        }

        float g = (n == p) ? 0.0f : BIGNEG;
        const float* fb = feats + (size_t)s * T * TAGS + n;
        uint8_t* bpb_l = bpB + (size_t)s * blocksB * 256 + p * 32 + (n >> 1) * 8;

#define KLEAF_B(r) { \
        int rot_ = SWZ_I(__float_as_int(g), r); \
        float lv_ = __int_as_float(rot_) + trowR[r]; \
        k##r = __int_as_float((__float_as_int(lv_) & ~7) | rsrc[r]); }

#define STEP_B(TI, FEAT, ACCST) { \
        const int t_ = (TI); \
        float k0, k1, k2, k3, k4, k5, k6, k7; \
        { float lv_ = g + trowR[0]; \
          k0 = __int_as_float((__float_as_int(lv_) & ~7) | rsrc[0]); } \
        KLEAF_B(1) KLEAF_B(2) KLEAF_B(3) KLEAF_B(4) \
        KLEAF_B(5) KLEAF_B(6) KLEAF_B(7) \
        const float p1_ = maxf3(k0, k1, k2); \
        const float p2_ = maxf3(k3, k4, k5); \
        const float p3_ = maxf3(k6, k7, p1_); \
        const float mm_ = fmaxf(p2_, p3_); \
        const int idx_  = (__float_as_int(mm_) & 7) ^ 7; \
        const int pidx_ = SWZ_I(idx_, 1); \
        const uint32_t byte_ = (uint32_t)(odd ? (pidx_ | (idx_ << 4)) \
                                              : (idx_ | (pidx_ << 4))); \
        ACCST; \
        g = (t_ < len) ? (mm_ + (FEAT)) : g; }

#define PH_B(USE, LD, T0) { \
        GLOAD8(LD, fb + (size_t)min((T0) + 16, T - 8) * TAGS); \
        WAITP \
        uint32_t accl, acch; \
        STEP_B((T0) + 0, USE[0], accl = byte_) \
        STEP_B((T0) + 1, USE[1], accl |= byte_ << 8) \
        STEP_B((T0) + 2, USE[2], accl |= byte_ << 16) \
        STEP_B((T0) + 3, USE[3], accl |= byte_ << 24) \
        STEP_B((T0) + 4, USE[4], acch = byte_) \
        STEP_B((T0) + 5, USE[5], acch |= byte_ << 8) \
        STEP_B((T0) + 6, USE[6], acch |= byte_ << 16) \
        STEP_B((T0) + 7, USE[7], acch |= byte_ << 24) \
        if ((T0) < T) { \
            if (!odd) *(uint2*)(bpb_l + (size_t)(((T0) - H) >> 3) * 256) \
                          = make_uint2(accl, acch); } }

        PINFENCE
        float xb[8], yb[8], zb[8];
        GLOAD8(xb, fb + (size_t)H * TAGS);
        GLOAD8(yb, fb + (size_t)min(H + 8, T - 8) * TAGS);

        for (int t0 = H; t0 < len; t0 += 24) {
            PH_B(xb, zb, t0)
            PH_B(yb, xb, t0 + 8)
            PH_B(zb, yb, t0 + 16)
        }
#undef KLEAF_B
#undef STEP_B
#undef PH_B

        gws[(size_t)s * 64 + lane] = g;
    }
}

// ===========================================================================
// K2: seam + terminal + blocked backtraces, ping-pong prefetch restored
// (R10's serial per-block loads cost ~50 us; R9's double-buffer was ~30).
// ===========================================================================
__global__ __launch_bounds__(64, 1) void crf_split_bt(
    const int*     __restrict__ lengths,
    const float*   __restrict__ trans,
    const uint8_t* __restrict__ bpA,
    const uint8_t* __restrict__ bpB,
    const float*   __restrict__ fvA,
    const float*   __restrict__ gws,
    float*         __restrict__ out_scores,
    float*         __restrict__ out_path,
    int B, int T, int H)
{
    const int rb = (B + 63) >> 6;
    const bool roleB = ((int)blockIdx.x < rb);
    const int s = (roleB ? (int)blockIdx.x : (int)blockIdx.x - rb) * 64 + threadIdx.x;
    if (s >= B) return;
    const int len = lengths[s];
    const int blocksA = (H + 6) >> 3;
    const int blocksB = (T - H + 7) >> 3;

    float fa[8];
    {
        const float4* f4 = (const float4*)(fvA + (size_t)s * 8);
        float4 a = f4[0], c = f4[1];
        fa[0]=a.x; fa[1]=a.y; fa[2]=a.z; fa[3]=a.w;
        fa[4]=c.x; fa[5]=c.y; fa[6]=c.z; fa[7]=c.w;
    }
    const float* gr = gws + (size_t)s * 64;
    float fv[8];
    if (len > H) {
#pragma unroll
        for (int nn = 0; nn < 8; ++nn) fv[nn] = fa[0] + gr[nn];
#pragma unroll
        for (int pp = 1; pp < 8; ++pp)
#pragma unroll
            for (int nn = 0; nn < 8; ++nn)
                fv[nn] = fmaxf(fv[nn], fa[pp] + gr[pp * 8 + nn]);
    } else {
#pragma unroll
        for (int nn = 0; nn < 8; ++nn) fv[nn] = fa[nn];
    }

    float best = fv[0] + trans[STOP_TAG * TAGS + 0];
    int ltag = 0;
#pragma unroll
    for (int nn = 1; nn < 8; ++nn) {
        const float tv = fv[nn] + trans[STOP_TAG * TAGS + nn];
        if (tv > best) { best = tv; ltag = nn; }
    }
    int pstar = 0;
    if (len > H) {
        float bb = fa[0] + gr[ltag];
#pragma unroll
        for (int pp = 1; pp < 8; ++pp) {
            const float v = fa[pp] + gr[pp * 8 + ltag];
            if (v > bb) { bb = v; pstar = pp; }
        }
    }

    float* orow = out_path + (size_t)s * T;

#define CHASE(J) { \
        const uint32_t sA_ = (tag & 2) ? d[2 + ((J) >> 2)] : d[((J) >> 2)]; \
        const uint32_t sB_ = (tag & 2) ? d[6 + ((J) >> 2)] : d[4 + ((J) >> 2)]; \
        const uint32_t sel_ = (tag & 4) ? sB_ : sA_; \
        tag = (int)((sel_ >> (8 * ((J) & 3) + 4 * (tag & 1))) & 7); }

    if (roleB) {
        out_scores[s] = best;
        int tag = ltag;
        const uint8_t* bb8 = bpB + (size_t)s * blocksB * 256 + pstar * 32;
        uint4 a0, b0, a1, b1;
        auto ldB = [&](int k, uint4& qa, uint4& qb) {
            if (k < 0) return;
            qa = *(const uint4*)(bb8 + (size_t)k * 256);
            qb = *(const uint4*)(bb8 + (size_t)k * 256 + 16);
        };
        auto cpB = [&](int k, const uint4& qa, const uint4& qb) {
            const uint32_t d[8] = {qa.x, qa.y, qa.z, qa.w, qb.x, qb.y, qb.z, qb.w};
            float buf[8];
#pragma unroll
            for (int u = 7; u >= 0; --u) {
                const int t = H + 8 * k + u;
                if (t < T) {
                    const bool act = t < len;
                    buf[u] = act ? (float)tag : 0.0f;
                    if (act) CHASE(u)
                }
            }
            const int t0 = H + 8 * k;
#pragma unroll
            for (int j = 0; j < 8; j += 4) {
                const int t = t0 + j;
                if (t + 3 < T) {
                    *(float4*)(orow + t) = make_float4(buf[j], buf[j+1], buf[j+2], buf[j+3]);
                } else {
#pragma unroll
                    for (int q = 0; q < 4; ++q)
                        if (t + q < T) orow[t + q] = buf[j + q];
                }
            }
        };
        int k = blocksB - 1;
        ldB(k, a0, b0); ldB(k - 1, a1, b1);
        for (; k >= 0; k -= 2) {
            cpB(k, a0, b0); ldB(k - 2, a0, b0);
            if (k - 1 >= 0) cpB(k - 1, a1, b1);
            ldB(k - 3, a1, b1);
        }
    } else {
        const int lenA = min(len, H);
        int tag = (len > H) ? pstar : ltag;
        const uint8_t* ab8 = bpA + (size_t)s * blocksA * 32;
        uint4 a0, b0, a1, b1;
        auto ldA = [&](int k, uint4& qa, uint4& qb) {
            if (k < 0) return;
            qa = *(const uint4*)(ab8 + (size_t)k * 32);
            qb = *(const uint4*)(ab8 + (size_t)k * 32 + 16);
        };
        auto cpA = [&](int k, const uint4& qa, const uint4& qb) {
            const uint32_t d[8] = {qa.x, qa.y, qa.z, qa.w, qb.x, qb.y, qb.z, qb.w};
#pragma unroll
            for (int u = 7; u >= 0; --u) {
                const int t = 8 * k + 1 + u;
                if (t < H) {
                    const bool act = t < lenA;
                    orow[t] = act ? (float)tag : 0.0f;
                    if (act) CHASE(u)
                }
            }
        };
        int k = blocksA - 1;
        ldA(k, a0, b0); ldA(k - 1, a1, b1);
        for (; k >= 0; k -= 2) {
            cpA(k, a0, b0); ldA(k - 2, a0, b0);
            if (k - 1 >= 0) cpA(k - 1, a1, b1);
            ldA(k - 3, a1, b1);
        }
        orow[0] = (float)tag;
    }
#undef CHASE
}

// ===========================================================================
// Ablation kernels — diagnostics only (outputs to ws keepalive; their
// per-dispatch dur_us in the rocprof table is the measurement).
// ===========================================================================

// Clock calibrator: 8 dependent v_add_f32 per iter; 1104 iters = 8832 dep
// adds ~ 4cyc each = ~35k cyc = ~14.7us @ 2.4GHz. 2x that => ~1.2GHz clock.
__global__ __launch_bounds__(64, 1) void crf_abl_chain(
    float* __restrict__ scratch, int iters)
{
    float x = (float)threadIdx.x * 1.0000001f;
    for (int i = 0; i < iters; ++i) {
#pragma unroll
        for (int j = 0; j < 8; ++j)
            x = x + 0.9999999f;
    }
    scratch[blockIdx.x * 64 + threadIdx.x] = x;
}

// Pure-VALU half-A step loop: no VMEM at all. Measures the DPP/pack/max wall.
__global__ __launch_bounds__(64, 1) void crf_abl_valu(
    const float* __restrict__ trans,
    float* __restrict__ scratch, int steps, int lenA)
{
    const int lane = threadIdx.x & 63;
    const int n    = lane & 15;
    const int m    = n & 7;
    const bool odd = (n & 1);

    int srcv[8];
    srcv[0] = n;
    srcv[1] = DPP_I(n, 0x121);  srcv[2] = DPP_I(n, 0x122);
    srcv[3] = DPP_I(n, 0x123);  srcv[4] = DPP_I(n, 0x124);
    srcv[5] = DPP_I(n, 0x125);  srcv[6] = DPP_I(n, 0x126);
    srcv[7] = DPP_I(n, 0x127);

    float trowR[8];
    int   rsrc[8];
#pragma unroll
    for (int r = 0; r < 8; ++r) {
        const int sq = srcv[r] & 7;
        trowR[r] = trans[m * TAGS + sq];
        rsrc[r]  = sq ^ 7;
    }

    float fv = trans[m * TAGS + START_TAG];

#define KLEAF_V(r, ctrl) { \
        int rot_ = DPP_I(__float_as_int(fv), (ctrl)); \
        float lv_ = __int_as_float(rot_) + trowR[r]; \
        k##r = __int_as_float((__float_as_int(lv_) & ~7) | rsrc[r]); }

#define STEP_V(TI, FEAT, ACCST) { \
        const int t_ = (TI); \
        float k0, k1, k2, k3, k4, k5, k6, k7; \
        { float lv_ = fv + trowR[0]; \
          k0 = __int_as_float((__float_as_int(lv_) & ~7) | rsrc[0]); } \
        KLEAF_V(1, 0x121) KLEAF_V(2, 0x122) KLEAF_V(3, 0x123) \
        KLEAF_V(4, 0x124) KLEAF_V(5, 0x125) KLEAF_V(6, 0x126) \
        KLEAF_V(7, 0x127) \
        const float p1_ = maxf3(k0, k1, k2); \
        const float p2_ = maxf3(k3, k4, k5); \
        const float p3_ = maxf3(k6, k7, p1_); \
        const float mm_ = fmaxf(p2_, p3_); \
        const int idx_  = (__float_as_int(mm_) & 7) ^ 7; \
        const int pidx_ = DPP_I(idx_, 0xB1); \
        const uint32_t byte_ = (uint32_t)(odd ? (pidx_ | (idx_ << 4)) \
                                              : (idx_ | (pidx_ << 4))); \
        ACCST; \
        const float fvn_ = mm_ + (FEAT); \
        fv = (t_ < lenA) ? fvn_ : fv; }

    for (int t0 = 0; t0 < steps; t0 += 8) {
        uint32_t accl, acch;
        STEP_V(t0 + 0, trowR[0], accl = byte_)
        STEP_V(t0 + 1, trowR[1], accl |= byte_ << 8)
        STEP_V(t0 + 2, trowR[2], accl |= byte_ << 16)
        STEP_V(t0 + 3, trowR[3], accl |= byte_ << 24)
        STEP_V(t0 + 4, trowR[4], acch = byte_)
        STEP_V(t0 + 5, trowR[5], acch |= byte_ << 8)
        STEP_V(t0 + 6, trowR[6], acch |= byte_ << 16)
        STEP_V(t0 + 7, trowR[7], acch |= byte_ << 24)
        asm volatile("" :: "v"(accl), "v"(acch));   // keepalive (rule #17)
    }
#undef KLEAF_V
#undef STEP_V

    scratch[blockIdx.x * 64 + threadIdx.x] = fv;
}

// Half-A step loop + pinned feat loads + counted vmcnt waits, NO stores.
__global__ __launch_bounds__(64, 1) void crf_abl_ld(
    const float* __restrict__ feats,
    const float* __restrict__ trans,
    float* __restrict__ scratch,
    int B, int T, int steps, int lenA)
{
    const int lane = threadIdx.x & 63;
    const int grp  = lane >> 4;
    const int n    = lane & 15;
    const int m    = n & 7;
    const bool odd = (n & 1);
    const int b    = min((int)blockIdx.x * 4 + grp, B - 1);

    int srcv[8];
    srcv[0] = n;
    srcv[1] = DPP_I(n, 0x121);  srcv[2] = DPP_I(n, 0x122);
    srcv[3] = DPP_I(n, 0x123);  srcv[4] = DPP_I(n, 0x124);
    srcv[5] = DPP_I(n, 0x125);  srcv[6] = DPP_I(n, 0x126);
    srcv[7] = DPP_I(n, 0x127);

    float trowR[8];
    int   rsrc[8];
#pragma unroll
    for (int r = 0; r < 8; ++r) {
        const int sq = srcv[r] & 7;
        trowR[r] = trans[m * TAGS + sq];
        rsrc[r]  = sq ^ 7;
    }

    const float* fb = feats + (size_t)b * T * TAGS + m;
    float fv = trans[m * TAGS + START_TAG] + fb[0];

#define KLEAF_L(r, ctrl) { \
        int rot_ = DPP_I(__float_as_int(fv), (ctrl)); \
        float lv_ = __int_as_float(rot_) + trowR[r]; \
        k##r = __int_as_float((__float_as_int(lv_) & ~7) | rsrc[r]); }

#define STEP_L(TI, FEAT, ACCST) { \
        const int t_ = (TI); \
        float k0, k1, k2, k3, k4, k5, k6, k7; \
        { float lv_ = fv + trowR[0]; \
          k0 = __int_as_float((__float_as_int(lv_) & ~7) | rsrc[0]); } \
        KLEAF_L(1, 0x121) KLEAF_L(2, 0x122) KLEAF_L(3, 0x123) \
        KLEAF_L(4, 0x124) KLEAF_L(5, 0x125) KLEAF_L(6, 0x126) \
        KLEAF_L(7, 0x127) \
        const float p1_ = maxf3(k0, k1, k2); \
        const float p2_ = maxf3(k3, k4, k5); \
        const float p3_ = maxf3(k6, k7, p1_); \
        const float mm_ = fmaxf(p2_, p3_); \
        const int idx_  = (__float_as_int(mm_) & 7) ^ 7; \
        const int pidx_ = DPP_I(idx_, 0xB1); \
        const uint32_t byte_ = (uint32_t)(odd ? (pidx_ | (idx_ << 4)) \
                                              : (idx_ | (pidx_ << 4))); \
        ACCST; \
        const float fvn_ = mm_ + (FEAT); \
        fv = (t_ < lenA) ? fvn_ : fv; }

#define PH_L(USE, LD, T0) { \
        GLOAD8(LD, fb + (size_t)min((T0) + 16, T - 8) * TAGS); \
        WAITP \
        uint32_t accl, acch; \
        STEP_L((T0) + 0, USE[0], accl = byte_) \
        STEP_L((T0) + 1, USE[1], accl |= byte_ << 8) \
        STEP_L((T0) + 2, USE[2], accl |= byte_ << 16) \
        STEP_L((T0) + 3, USE[3], accl |= byte_ << 24) \
        STEP_L((T0) + 4, USE[4], acch = byte_) \
        STEP_L((T0) + 5, USE[5], acch |= byte_ << 8) \
        STEP_L((T0) + 6, USE[6], acch |= byte_ << 16) \
        STEP_L((T0) + 7, USE[7], acch |= byte_ << 24) \
        asm volatile("" :: "v"(accl), "v"(acch)); }

    PINFENCE
    float xb[8], yb[8], zb[8];
    GLOAD8(xb, fb + (size_t)1 * TAGS);
    GLOAD8(yb, fb + (size_t)min(9, T - 8) * TAGS);

    for (int t0 = 1; t0 < steps; t0 += 24) {
        PH_L(xb, zb, t0)
        PH_L(yb, xb, t0 + 8)
        PH_L(zb, yb, t0 + 16)
    }
#undef KLEAF_L
#undef STEP_L
#undef PH_L

    scratch[blockIdx.x * 64 + threadIdx.x] = fv;
}

// ===========================================================================
// Fallback (ws too small): R8 fused kernel verbatim.
// ===========================================================================
__global__ __launch_bounds__(64, 1) void crf_fused_small(
    const float* __restrict__ feats,
    const int*   __restrict__ lengths,
    const float* __restrict__ trans,
    float*       __restrict__ out_scores,
    float*       __restrict__ out_path,
    uint8_t*     __restrict__ bp4,
    int B, int T)
{
    const int lane = threadIdx.x & 63;
    const int grp  = lane >> 4;
    const int n    = lane & 15;
    const int m    = n & 7;
    const bool odd = (n & 1);
    const int b4   = blockIdx.x * 4;
    const int b    = min(b4 + grp, B - 1);

    const int len = lengths[b];
    const int l0 = lengths[min(b4 + 0, B - 1)];
    const int l1 = lengths[min(b4 + 1, B - 1)];
    const int l2 = lengths[min(b4 + 2, B - 1)];
    const int l3 = lengths[min(b4 + 3, B - 1)];
    const int maxlen = max(max(l0, l1), max(l2, l3));

    int srcv[8];
    srcv[0] = n;
    srcv[1] = DPP_I(n, 0x121);  srcv[2] = DPP_I(n, 0x122);
    srcv[3] = DPP_I(n, 0x123);  srcv[4] = DPP_I(n, 0x124);
    srcv[5] = DPP_I(n, 0x125);  srcv[6] = DPP_I(n, 0x126);
    srcv[7] = DPP_I(n, 0x127);

    float trowR[8];
    int   rsrc[8];
#pragma unroll
    for (int r = 0; r < 8; ++r) {
        const int sq = srcv[r] & 7;
        trowR[r] = trans[m * TAGS + sq];
        rsrc[r]  = sq ^ 7;
    }

    const float* fb = feats + (size_t)b * T * TAGS + m;
    uint8_t* bpb = bp4 + (size_t)b * T * 4 + (n >> 1);
    const bool store_lane = (n < 8) && !odd;

    float fv = trans[m * TAGS + START_TAG] + fb[0];

#define KLEAF_S(r, ctrl) { \
        int rot_ = DPP_I(__float_as_int(fv), (ctrl)); \
        float lv_ = __int_as_float(rot_) + trowR[r]; \
        k##r = __int_as_float((__float_as_int(lv_) & ~7) | rsrc[r]); }

#define STEP_S(TI, FEAT) { \
        const int t_ = (TI); \
        float k0, k1, k2, k3, k4, k5, k6, k7; \
        { float lv_ = fv + trowR[0]; \
          k0 = __int_as_float((__float_as_int(lv_) & ~7) | rsrc[0]); } \
        KLEAF_S(1, 0x121) KLEAF_S(2, 0x122) KLEAF_S(3, 0x123) \
        KLEAF_S(4, 0x124) KLEAF_S(5, 0x125) KLEAF_S(6, 0x126) \
        KLEAF_S(7, 0x127) \
        const float p1_ = maxf3(k0, k1, k2); \
        const float p2_ = maxf3(k3, k4, k5); \
        const float p3_ = maxf3(k6, k7, p1_); \
        const float mm_ = fmaxf(p2_, p3_); \
        const int   idx_  = (__float_as_int(mm_) & 7) ^ 7; \
        const int   pidx_ = DPP_I(idx_, 0xB1); \
        const int   lo_   = odd ? pidx_ : idx_; \
        const int   hi_   = odd ? idx_ : pidx_; \
        const float fvn_  = mm_ + (FEAT); \
        fv = (t_ < len) ? fvn_ : fv; \
        if (t_ < T) { \
            if (store_lane) \
                bpb[(size_t)t_ * 4] = (uint8_t)(lo_ | (hi_ << 4)); \
        } }

    float fc[8], fn[8];
#pragma unroll
    for (int i = 0; i < 8; ++i)
        fc[i] = fb[(size_t)min(1 + i, T - 1) * TAGS];

    for (int t0 = 1; t0 < maxlen; t0 += 8) {
#pragma unroll
        for (int i = 0; i < 8; ++i)
            fn[i] = fb[(size_t)min(t0 + 8 + i, T - 1) * TAGS];

        STEP_S(t0 + 0, fc[0]) STEP_S(t0 + 1, fc[1])
        STEP_S(t0 + 2, fc[2]) STEP_S(t0 + 3, fc[3])
        STEP_S(t0 + 4, fc[4]) STEP_S(t0 + 5, fc[5])
        STEP_S(t0 + 6, fc[6]) STEP_S(t0 + 7, fc[7])

#pragma unroll
        for (int i = 0; i < 8; ++i) fc[i] = fn[i];
    }
#undef KLEAF_S
#undef STEP_S

    const float term = fv + trans[STOP_TAG * TAGS + m];
    float kk = __int_as_float((__float_as_int(term) & ~7) | (m ^ 7));
    kk = fmaxf(kk, __int_as_float(DPP_I(__float_as_int(kk), 0x124)));
    kk = fmaxf(kk, __int_as_float(DPP_I(__float_as_int(kk), 0x122)));
    kk = fmaxf(kk, __int_as_float(DPP_I(__float_as_int(kk), 0x121)));
    int tag = (__float_as_int(kk) & 7) ^ 7;

    if (n == 0)
        out_scores[b] = kk;

    __builtin_amdgcn_s_waitcnt(0);
    __builtin_amdgcn_sched_barrier(0);

    if (n == 0) {
        const uint32_t* rw = (const uint32_t*)(bp4 + (size_t)b * T * 4);
        float* orow = out_path + (size_t)b * T;
        const int NB = (T + 15) / 16;
        uint32_t wA[16], wB[16];

        auto loadblk = [&](int bi, uint32_t* w) {
            if (bi < 0) return;
#pragma unroll
            for (int j = 0; j < 4; ++j) {
                const int tb = min(bi * 16 + 4 * j, T - 4);
                *(uint4*)&w[4 * j] = *(const uint4*)&rw[tb];
            }
        };
        auto compblk = [&](int bi, uint32_t* w) {
            float buf[16];
#pragma unroll
            for (int u = 15; u >= 0; --u) {
                const int t = bi * 16 + u;
                if (t < T) {
                    const bool act = t < len;
                    buf[u] = act ? (float)tag : 0.0f;
                    if (act) tag = (int)((w[u] >> (4 * tag)) & 15);
                }
            }
#pragma unroll
            for (int j = 0; j < 16; j += 4) {
                const int t = bi * 16 + j;
                if (t + 3 < T)
                    *(float4*)(orow + t) = make_float4(buf[j], buf[j+1], buf[j+2], buf[j+3]);
            }
        };

        int bi = NB - 1;
        loadblk(bi, wA);
        loadblk(bi - 1, wB);
        for (; bi >= 0; bi -= 2) {
            compblk(bi, wA);
            loadblk(bi - 2, wA);
            if (bi - 1 >= 0) compblk(bi - 1, wB);
            loadblk(bi - 3, wB);
        }
    }
}

extern "C" void kernel_launch(void* const* d_in, const int* in_sizes, int n_in,
                              void* d_out, int out_size, void* d_ws, size_t ws_size,
                              hipStream_t stream)
{
    const float* feats   = (const float*)d_in[0];
    const int*   lengths = (const int*)d_in[1];
    const float* trans   = (const float*)d_in[2];
    const int B = in_sizes[1];
    const int T = in_sizes[0] / (B * TAGS);

    float* out_scores = (float*)d_out;       // [B]
    float* out_path   = (float*)d_out + B;   // [B, T] tags as floats

    // pick smallest H (multiple of 16) whose workspace fits
    int H = ((T / 2) + 15) & ~15;
    size_t need = 0;
    bool ok = false;
    for (; H + 16 < T; H += 16) {
        const size_t blocksA = (size_t)((H + 6) >> 3);
        const size_t blocksB = (size_t)((T - H + 7) >> 3);
        need = (size_t)B * (blocksA * 32 + blocksB * 256 + 32 + 256);
        if (need <= ws_size) { ok = true; break; }
    }

    if (ok && T > 64 && (T & 3) == 0) {
        const size_t blocksA = (size_t)((H + 6) >> 3);
        const size_t blocksB = (size_t)((T - H + 7) >> 3);
        uint8_t* bpA  = (uint8_t*)d_ws;
        uint8_t* bpB  = bpA + (size_t)B * blocksA * 32;
        float*   fvAo = (float*)(bpB + (size_t)B * blocksB * 256);
        float*   gws  = fvAo + (size_t)B * 8;
        const int ABLK = (B + 3) / 4;

        crf_split_fwd<<<ABLK + B, 64, 0, stream>>>(
            feats, lengths, trans, bpA, bpB, fvAo, gws, B, T, H, ABLK);

        const int rb = (B + 63) >> 6;
        crf_split_bt<<<2 * rb, 64, 0, stream>>>(
            lengths, trans, bpA, bpB, fvAo, gws, out_scores, out_path, B, T, H);
    } else {
        uint8_t* bp4 = (uint8_t*)d_ws;       // [B][T] 4B words
        crf_fused_small<<<(B + 3) / 4, 64, 0, stream>>>(
            feats, lengths, trans, out_scores, out_path, bp4, B, T);
    }

    // Diagnostics (run AFTER the production kernels; write only ws scratch,
    // which K1 fully regenerates before K2 reads it on the next replay).
    float* abl = (float*)d_ws;
    crf_abl_chain<<<256, 64, 0, stream>>>(abl, 1104);
    crf_abl_valu<<<256, 64, 0, stream>>>(trans, abl + 16384, 368, 364);
    crf_abl_ld<<<256, 64, 0, stream>>>(feats, trans, abl + 32768, B, T, 368, 364);
}

// Round 12
// 123.160 us; speedup vs baseline: 1.8536x; 1.8536x over previous
//
#include <hip/hip_runtime.h>
#include <stdint.h>

#define TAGS 10
#define START_TAG 8
#define STOP_TAG 9
#define NEGV (-10000.0f)
#define BIGNEG (-1.0e9f)

// DPP within 16-lane rows: ROW_ROR:r = 0x120+r, QUAD_PERM[1,0,3,2] = 0xB1.
#define DPP_I(x, ctrl) __builtin_amdgcn_update_dpp(0, (x), (ctrl), 0xF, 0xF, true)
// ds_swizzle BitMode XOR-r within 32-lane halves.
#define SWZ_I(x, r) __builtin_amdgcn_ds_swizzle((x), (((r) << 10) | 0x1F))

__device__ __forceinline__ float maxf3(float a, float b, float c) {
    return fmaxf(fmaxf(a, b), c);   // folds to v_max3_f32
}

// Inline-asm feat loads: structurally pinned (regalloc cannot sink them).
#define GLOADI(dst, base, OFF) \
    asm volatile("global_load_dword %0, %1, off offset:" #OFF \
                 : "=v"(dst) : "v"(base))
#define GLOAD8(BUF, BASE) { \
    const float* gb_ = (BASE); \
    GLOADI(BUF[0], gb_, 0);   GLOADI(BUF[1], gb_, 40); \
    GLOADI(BUF[2], gb_, 80);  GLOADI(BUF[3], gb_, 120); \
    GLOADI(BUF[4], gb_, 160); GLOADI(BUF[5], gb_, 200); \
    GLOADI(BUF[6], gb_, 240); GLOADI(BUF[7], gb_, 280); }
// per-element clamped variant (backward chunk runs to the T boundary)
#define GLOAD8X(BUF, FB, TB) { \
    GLOADI(BUF[0], (FB) + (size_t)min((TB) + 0, T - 1) * TAGS, 0); \
    GLOADI(BUF[1], (FB) + (size_t)min((TB) + 1, T - 1) * TAGS, 0); \
    GLOADI(BUF[2], (FB) + (size_t)min((TB) + 2, T - 1) * TAGS, 0); \
    GLOADI(BUF[3], (FB) + (size_t)min((TB) + 3, T - 1) * TAGS, 0); \
    GLOADI(BUF[4], (FB) + (size_t)min((TB) + 4, T - 1) * TAGS, 0); \
    GLOADI(BUF[5], (FB) + (size_t)min((TB) + 5, T - 1) * TAGS, 0); \
    GLOADI(BUF[6], (FB) + (size_t)min((TB) + 6, T - 1) * TAGS, 0); \
    GLOADI(BUF[7], (FB) + (size_t)min((TB) + 7, T - 1) * TAGS, 0); }
#define WAITP { asm volatile("s_waitcnt vmcnt(16)" ::: "memory"); \
                __builtin_amdgcn_sched_barrier(0); }
#define PINFENCE __builtin_amdgcn_sched_barrier(0);

// ===========================================================================
// K1: 3-chunk forward. [0,ABLK): chunk1 = true Viterbi t in [0,G), packed
// 4 seqs/wave (R11 half-A, G-bounded). [ABLK,ABLK+CBLK): chunk3 = BACKWARD
// Viterbi t in [2G-1, T), packed 4 seqs/wave, per-seq activation at len-1
// (init h = STOP row; no basis needed — boundary condition known at the end).
// [ABLK+CBLK, +B): chunk2 = 8-basis recurrence t in [G, min(len,2G)), 1 seq/
// wave (R11 half-B). Outputs: bpA/bpB/bpC nibble blocks, fvAo (fv at G-1),
// gws (basis g at min(len,2G)-1), hws (h at 2G-1).
// ===========================================================================
__global__ __launch_bounds__(64, 1) void crf_split3_fwd(
    const float* __restrict__ feats,
    const int*   __restrict__ lengths,
    const float* __restrict__ trans,
    uint8_t*     __restrict__ bpA,
    uint8_t*     __restrict__ bpB,
    uint8_t*     __restrict__ bpC,
    float*       __restrict__ fvAo,
    float*       __restrict__ gws,
    float*       __restrict__ hws,
    int B, int T, int G, int ABLK, int CBLK, int NCpad)
{
    const int lane = threadIdx.x & 63;
    const int G2 = 2 * G;

    if ((int)blockIdx.x < ABLK) {
        // ---------------- chunk 1: forward [0, G) ----------------
        const int grp  = lane >> 4;
        const int n    = lane & 15;
        const int m    = n & 7;
        const bool odd = (n & 1);
        const int b4   = blockIdx.x * 4;
        const int b    = min(b4 + grp, B - 1);

        const int len  = lengths[b];
        const int lenA = min(len, G);
        const int l0 = lengths[min(b4 + 0, B - 1)];
        const int l1 = lengths[min(b4 + 1, B - 1)];
        const int l2 = lengths[min(b4 + 2, B - 1)];
        const int l3 = lengths[min(b4 + 3, B - 1)];
        const int HA = min(max(max(l0, l1), max(l2, l3)), G);
        const int blocksA = (G + 6) >> 3;

        int srcv[8];
        srcv[0] = n;
        srcv[1] = DPP_I(n, 0x121);  srcv[2] = DPP_I(n, 0x122);
        srcv[3] = DPP_I(n, 0x123);  srcv[4] = DPP_I(n, 0x124);
        srcv[5] = DPP_I(n, 0x125);  srcv[6] = DPP_I(n, 0x126);
        srcv[7] = DPP_I(n, 0x127);

        float trowR[8];
        int   rsrc[8];
#pragma unroll
        for (int r = 0; r < 8; ++r) {
            const int sq = srcv[r] & 7;
            trowR[r] = trans[m * TAGS + sq];
            rsrc[r]  = sq ^ 7;
        }

        const float* fb = feats + (size_t)b * T * TAGS + m;
        uint8_t* bpa_l = bpA + (size_t)b * blocksA * 32 + ((n >> 1) & 3) * 8;
        const bool stl = (n < 8) && !odd;

        float fv = trans[m * TAGS + START_TAG] + fb[0];

#define KLEAF_A(r, ctrl) { \
        int rot_ = DPP_I(__float_as_int(fv), (ctrl)); \
        float lv_ = __int_as_float(rot_) + trowR[r]; \
        k##r = __int_as_float((__float_as_int(lv_) & ~7) | rsrc[r]); }

#define STEP_A(TI, FEAT, ACCST) { \
        const int t_ = (TI); \
        float k0, k1, k2, k3, k4, k5, k6, k7; \
        { float lv_ = fv + trowR[0]; \
          k0 = __int_as_float((__float_as_int(lv_) & ~7) | rsrc[0]); } \
        KLEAF_A(1, 0x121) KLEAF_A(2, 0x122) KLEAF_A(3, 0x123) \
        KLEAF_A(4, 0x124) KLEAF_A(5, 0x125) KLEAF_A(6, 0x126) \
        KLEAF_A(7, 0x127) \
        const float p1_ = maxf3(k0, k1, k2); \
        const float p2_ = maxf3(k3, k4, k5); \
        const float p3_ = maxf3(k6, k7, p1_); \
        const float mm_ = fmaxf(p2_, p3_); \
        const int idx_  = (__float_as_int(mm_) & 7) ^ 7; \
        const int pidx_ = DPP_I(idx_, 0xB1); \
        const uint32_t byte_ = (uint32_t)(odd ? (pidx_ | (idx_ << 4)) \
                                              : (idx_ | (pidx_ << 4))); \
        ACCST; \
        const float fvn_ = mm_ + (FEAT); \
        fv = (t_ < lenA) ? fvn_ : fv; }

#define PH_A(USE, LD, T0) { \
        GLOAD8(LD, fb + (size_t)min((T0) + 16, T - 8) * TAGS); \
        WAITP \
        uint32_t accl, acch; \
        STEP_A((T0) + 0, USE[0], accl = byte_) \
        STEP_A((T0) + 1, USE[1], accl |= byte_ << 8) \
        STEP_A((T0) + 2, USE[2], accl |= byte_ << 16) \
        STEP_A((T0) + 3, USE[3], accl |= byte_ << 24) \
        STEP_A((T0) + 4, USE[4], acch = byte_) \
        STEP_A((T0) + 5, USE[5], acch |= byte_ << 8) \
        STEP_A((T0) + 6, USE[6], acch |= byte_ << 16) \
        STEP_A((T0) + 7, USE[7], acch |= byte_ << 24) \
        if ((T0) < G) { \
            if (stl) *(uint2*)(bpa_l + (size_t)(((T0) - 1) >> 3) * 32) \
                         = make_uint2(accl, acch); } }

        PINFENCE
        float xb[8], yb[8], zb[8];
        GLOAD8(xb, fb + (size_t)1 * TAGS);
        GLOAD8(yb, fb + (size_t)min(9, T - 8) * TAGS);

        for (int t0 = 1; t0 < HA; t0 += 24) {
            PH_A(xb, zb, t0)
            PH_A(yb, xb, t0 + 8)
            PH_A(zb, yb, t0 + 16)
        }
#undef KLEAF_A
#undef STEP_A
#undef PH_A

        if (n < 8)
            fvAo[(size_t)b * 8 + m] = fv;
    } else if ((int)blockIdx.x < ABLK + CBLK) {
        // ---------------- chunk 3: backward [2G-1, T) ----------------
        const int grp  = lane >> 4;
        const int n    = lane & 15;
        const int m    = n & 7;
        const bool odd = (n & 1);
        const int c4   = (blockIdx.x - ABLK) * 4;
        const int b    = min(c4 + grp, B - 1);
        const int len  = lengths[b];
        const int lenm1 = len - 1;          // step t active iff t < len-1

        int srcv[8];
        srcv[0] = n;
        srcv[1] = DPP_I(n, 0x121);  srcv[2] = DPP_I(n, 0x122);
        srcv[3] = DPP_I(n, 0x123);  srcv[4] = DPP_I(n, 0x124);
        srcv[5] = DPP_I(n, 0x125);  srcv[6] = DPP_I(n, 0x126);
        srcv[7] = DPP_I(n, 0x127);

        // backward: h_t[m] = max_sq (feat_{t+1}[sq] + h_{t+1}[sq] + trans[sq][m])
        float trowC[8];
        int   rsrc[8];
#pragma unroll
        for (int r = 0; r < 8; ++r) {
            const int sq = srcv[r] & 7;
            trowC[r] = trans[sq * TAGS + m];
            rsrc[r]  = sq ^ 7;
        }

        float h = trans[STOP_TAG * TAGS + m];   // init at t = len-1
        const float* fb = feats + (size_t)b * T * TAGS + m;
        uint8_t* bpc_l = bpC + (size_t)b * NCpad * 32 + ((n >> 1) & 3) * 8;
        const bool stl = (n < 8) && !odd;

#define KLEAF_C(r, ctrl) { \
        int rot_ = DPP_I(__float_as_int(e_), (ctrl)); \
        float lv_ = __int_as_float(rot_) + trowC[r]; \
        k##r = __int_as_float((__float_as_int(lv_) & ~7) | rsrc[r]); }

#define STEP_C(K, J, FEAT, ACCST) { \
        const int t_ = G2 - 1 + 8 * (K) + (J); \
        const float e_ = h + (FEAT); \
        float k0, k1, k2, k3, k4, k5, k6, k7; \
        { float lv_ = e_ + trowC[0]; \
          k0 = __int_as_float((__float_as_int(lv_) & ~7) | rsrc[0]); } \
        KLEAF_C(1, 0x121) KLEAF_C(2, 0x122) KLEAF_C(3, 0x123) \
        KLEAF_C(4, 0x124) KLEAF_C(5, 0x125) KLEAF_C(6, 0x126) \
        KLEAF_C(7, 0x127) \
        const float p1_ = maxf3(k0, k1, k2); \
        const float p2_ = maxf3(k3, k4, k5); \
        const float p3_ = maxf3(k6, k7, p1_); \
        const float mm_ = fmaxf(p2_, p3_); \
        const int idx_  = (__float_as_int(mm_) & 7) ^ 7; \
        const int pidx_ = DPP_I(idx_, 0xB1); \
        const uint32_t byte_ = (uint32_t)(odd ? (pidx_ | (idx_ << 4)) \
                                              : (idx_ | (pidx_ << 4))); \
        ACCST; \
        h = (t_ < lenm1) ? mm_ : h; }

#define PH_C(USE, LD, K) { \
        GLOAD8X(LD, fb, G2 + 8 * ((K) - 2)) \
        WAITP \
        uint32_t accl, acch; \
        STEP_C(K, 7, USE[7], acch = byte_ << 24) \
        STEP_C(K, 6, USE[6], acch |= byte_ << 16) \
        STEP_C(K, 5, USE[5], acch |= byte_ << 8) \
        STEP_C(K, 4, USE[4], acch |= byte_) \
        STEP_C(K, 3, USE[3], accl = byte_ << 24) \
        STEP_C(K, 2, USE[2], accl |= byte_ << 16) \
        STEP_C(K, 1, USE[1], accl |= byte_ << 8) \
        STEP_C(K, 0, USE[0], accl |= byte_) \
        if (stl) *(uint2*)(bpc_l + (size_t)(K) * 32) = make_uint2(accl, acch); }

        PINFENCE
        float xb[8], yb[8], zb[8];
        GLOAD8X(xb, fb, G2 + 8 * (NCpad - 1))
        GLOAD8X(yb, fb, G2 + 8 * (NCpad - 2))

        for (int k = NCpad - 1; k >= 0; k -= 3) {   // NCpad multiple of 3
            PH_C(xb, zb, k)
            PH_C(yb, xb, k - 1)
            PH_C(zb, yb, k - 2)
        }
#undef KLEAF_C
#undef STEP_C
#undef PH_C

        if (n < 8)
            hws[(size_t)b * 8 + m] = h;     // h at t = 2G-1
    } else {
        // ---------------- chunk 2: 8-basis [G, min(len,2G)) ----------------
        const int s = blockIdx.x - ABLK - CBLK;
        if (s >= B) return;
        const int len = lengths[s];
        if (len <= G) return;
        const int lenB2 = min(len, G2);

        const int p    = lane >> 3;       // basis octet
        const int n    = lane & 7;        // tag
        const bool odd = (n & 1);
        const int blocksB = G >> 3;

        float trowR[8];
        int   rsrc[8];
#pragma unroll
        for (int r = 0; r < 8; ++r) {
            const int q = n ^ r;
            trowR[r] = trans[n * TAGS + q];
            rsrc[r]  = q ^ 7;
        }

        float g = (n == p) ? 0.0f : BIGNEG;   // basis e_p at t = G-1
        const float* fb = feats + (size_t)s * T * TAGS + n;
        uint8_t* bpb_l = bpB + (size_t)s * blocksB * 256 + p * 32 + (n >> 1) * 8;

#define KLEAF_B(r) { \
        int rot_ = SWZ_I(__float_as_int(g), r); \
        float lv_ = __int_as_float(rot_) + trowR[r]; \
        k##r = __int_as_float((__float_as_int(lv_) & ~7) | rsrc[r]); }

#define STEP_B(TI, FEAT, ACCST) { \
        const int t_ = (TI); \
        float k0, k1, k2, k3, k4, k5, k6, k7; \
        { float lv_ = g + trowR[0]; \
          k0 = __int_as_float((__float_as_int(lv_) & ~7) | rsrc[0]); } \
        KLEAF_B(1) KLEAF_B(2) KLEAF_B(3) KLEAF_B(4) \
        KLEAF_B(5) KLEAF_B(6) KLEAF_B(7) \
        const float p1_ = maxf3(k0, k1, k2); \
        const float p2_ = maxf3(k3, k4, k5); \
        const float p3_ = maxf3(k6, k7, p1_); \
        const float mm_ = fmaxf(p2_, p3_); \
        const int idx_  = (__float_as_int(mm_) & 7) ^ 7; \
        const int pidx_ = SWZ_I(idx_, 1); \
        const uint32_t byte_ = (uint32_t)(odd ? (pidx_ | (idx_ << 4)) \
                                              : (idx_ | (pidx_ << 4))); \
        ACCST; \
        g = (t_ < lenB2) ? (mm_ + (FEAT)) : g; }

#define PH_B(USE, LD, T0) { \
        GLOAD8(LD, fb + (size_t)min((T0) + 16, T - 8) * TAGS); \
        WAITP \
        uint32_t accl, acch; \
        STEP_B((T0) + 0, USE[0], accl = byte_) \
        STEP_B((T0) + 1, USE[1], accl |= byte_ << 8) \
        STEP_B((T0) + 2, USE[2], accl |= byte_ << 16) \
        STEP_B((T0) + 3, USE[3], accl |= byte_ << 24) \
        STEP_B((T0) + 4, USE[4], acch = byte_) \
        STEP_B((T0) + 5, USE[5], acch |= byte_ << 8) \
        STEP_B((T0) + 6, USE[6], acch |= byte_ << 16) \
        STEP_B((T0) + 7, USE[7], acch |= byte_ << 24) \
        if ((T0) < G2) { \
            if (!odd) *(uint2*)(bpb_l + (size_t)(((T0) - G) >> 3) * 256) \
                          = make_uint2(accl, acch); } }

        PINFENCE
        float xb[8], yb[8], zb[8];
        GLOAD8(xb, fb + (size_t)G * TAGS);
        GLOAD8(yb, fb + (size_t)min(G + 8, T - 8) * TAGS);

        for (int t0 = G; t0 < lenB2; t0 += 24) {
            PH_B(xb, zb, t0)
            PH_B(yb, xb, t0 + 8)
            PH_B(zb, yb, t0 + 16)
        }
#undef KLEAF_B
#undef STEP_B
#undef PH_B

        gws[(size_t)s * 64 + lane] = g;   // lane = p*8 + n
    }
}

// ===========================================================================
// Seam composition: fv2 = fv1 (x) g; score via h (len>2G) or STOP terminal.
// b2 = state at the relevant end; b1 = state at G-1. g/h read from MEMORY
// (runtime column index — avoids register-indexed arrays, rule #20).
// ===========================================================================
__device__ __forceinline__ void crf_compose(
    const float* __restrict__ fv1p, const float* __restrict__ gp,
    const float* __restrict__ hp, const float* __restrict__ trans,
    int len, int G, int G2, float& score, int& b1, int& b2)
{
    float fa[8];
    {
        const float4* f4 = (const float4*)fv1p;
        float4 a = f4[0], c = f4[1];
        fa[0]=a.x; fa[1]=a.y; fa[2]=a.z; fa[3]=a.w;
        fa[4]=c.x; fa[5]=c.y; fa[6]=c.z; fa[7]=c.w;
    }
    const bool hasB = len > G, hasC = len > G2;
    float fv2[8];
    if (hasB) {
#pragma unroll
        for (int nn = 0; nn < 8; ++nn) fv2[nn] = fa[0] + gp[nn];
#pragma unroll
        for (int pp = 1; pp < 8; ++pp)
#pragma unroll
            for (int nn = 0; nn < 8; ++nn)
                fv2[nn] = fmaxf(fv2[nn], fa[pp] + gp[pp * 8 + nn]);
    } else {
#pragma unroll
        for (int nn = 0; nn < 8; ++nn) fv2[nn] = fa[nn];
    }
    float best; int bb = 0;
    if (hasC) {
        best = fv2[0] + hp[0];
#pragma unroll
        for (int nn = 1; nn < 8; ++nn) {
            const float v = fv2[nn] + hp[nn];
            if (v > best) { best = v; bb = nn; }
        }
    } else {
        best = fv2[0] + trans[STOP_TAG * TAGS + 0];
#pragma unroll
        for (int nn = 1; nn < 8; ++nn) {
            const float v = fv2[nn] + trans[STOP_TAG * TAGS + nn];
            if (v > best) { best = v; bb = nn; }
        }
    }
    b2 = bb;
    if (hasB) {
        float bv = fa[0] + gp[bb]; int q0 = 0;
#pragma unroll
        for (int q = 1; q < 8; ++q) {
            const float v = fa[q] + gp[q * 8 + bb];
            if (v > bv) { bv = v; q0 = q; }
        }
        b1 = q0;
    } else {
        b1 = bb;
    }
    score = best;
}

// ===========================================================================
// K2: three backtrace roles per sequence (role = blockIdx / rb).
// role 0: chunk1 walk [0,G) backward from b1. role 1: chunk2 walk [G,2G)
// backward from b2 (basis b1). role 2: score write + chunk3 FORWARD walk
// [2G,T) via backward-bp: s_{t+1} = bb_t[s_t] from b2 at t = 2G-1.
// ===========================================================================
__global__ __launch_bounds__(64, 1) void crf_split3_bt(
    const int*     __restrict__ lengths,
    const float*   __restrict__ trans,
    const uint8_t* __restrict__ bpA,
    const uint8_t* __restrict__ bpB,
    const uint8_t* __restrict__ bpC,
    const float*   __restrict__ fvA,
    const float*   __restrict__ gws,
    const float*   __restrict__ hws,
    float*         __restrict__ out_scores,
    float*         __restrict__ out_path,
    int B, int T, int G, int NCpad)
{
    const int rb = (B + 63) >> 6;
    const int role = blockIdx.x / rb;
    const int s = (blockIdx.x % rb) * 64 + threadIdx.x;
    if (s >= B) return;
    const int len = lengths[s];
    const int G2 = 2 * G;
    const int blocksA = (G + 6) >> 3;
    const int blocksB = G >> 3;

    float score; int b1, b2;
    crf_compose(fvA + (size_t)s * 8, gws + (size_t)s * 64, hws + (size_t)s * 8,
                trans, len, G, G2, score, b1, b2);

    float* orow = out_path + (size_t)s * T;

#define CHASE(J) { \
        const uint32_t sA_ = (tag & 2) ? d[2 + ((J) >> 2)] : d[((J) >> 2)]; \
        const uint32_t sB_ = (tag & 2) ? d[6 + ((J) >> 2)] : d[4 + ((J) >> 2)]; \
        const uint32_t sel_ = (tag & 4) ? sB_ : sA_; \
        tag = (int)((sel_ >> (8 * ((J) & 3) + 4 * (tag & 1))) & 7); }

    if (role == 0) {
        // ---- chunk1 walk: [0, G) ----
        const int lenA = min(len, G);
        int tag = b1;
        const uint8_t* ab8 = bpA + (size_t)s * blocksA * 32;
        uint4 a0, c0, a1, c1;
        auto ldA = [&](int k, uint4& qa, uint4& qb) {
            if (k < 0) return;
            qa = *(const uint4*)(ab8 + (size_t)k * 32);
            qb = *(const uint4*)(ab8 + (size_t)k * 32 + 16);
        };
        auto cpA = [&](int k, const uint4& qa, const uint4& qb) {
            const uint32_t d[8] = {qa.x, qa.y, qa.z, qa.w, qb.x, qb.y, qb.z, qb.w};
#pragma unroll
            for (int u = 7; u >= 0; --u) {
                const int t = 8 * k + 1 + u;
                if (t < G) {
                    const bool act = t < lenA;
                    orow[t] = act ? (float)tag : 0.0f;
                    if (act) CHASE(u)
                }
            }
        };
        int k = blocksA - 1;
        ldA(k, a0, c0); ldA(k - 1, a1, c1);
        for (; k >= 0; k -= 2) {
            cpA(k, a0, c0); ldA(k - 2, a0, c0);
            if (k - 1 >= 0) cpA(k - 1, a1, c1);
            ldA(k - 3, a1, c1);
        }
        orow[0] = (float)tag;
    } else if (role == 1) {
        // ---- chunk2 walk: [G, 2G) ----
        const int lenB = min(len, G2);
        int tag = b2;
        const uint8_t* bb8 = bpB + (size_t)s * blocksB * 256 + b1 * 32;
        uint4 a0, c0, a1, c1;
        auto ldB = [&](int k, uint4& qa, uint4& qb) {
            if (k < 0) return;
            qa = *(const uint4*)(bb8 + (size_t)k * 256);
            qb = *(const uint4*)(bb8 + (size_t)k * 256 + 16);
        };
        auto cpB = [&](int k, const uint4& qa, const uint4& qb) {
            const uint32_t d[8] = {qa.x, qa.y, qa.z, qa.w, qb.x, qb.y, qb.z, qb.w};
            float buf[8];
#pragma unroll
            for (int u = 7; u >= 0; --u) {
                const int t = G + 8 * k + u;
                const bool act = t < lenB;
                buf[u] = act ? (float)tag : 0.0f;
                if (act) CHASE(u)
            }
            const int t0 = G + 8 * k;
            *(float4*)(orow + t0)     = make_float4(buf[0], buf[1], buf[2], buf[3]);
            *(float4*)(orow + t0 + 4) = make_float4(buf[4], buf[5], buf[6], buf[7]);
        };
        int k = blocksB - 1;
        ldB(k, a0, c0); ldB(k - 1, a1, c1);
        for (; k >= 0; k -= 2) {
            cpB(k, a0, c0); ldB(k - 2, a0, c0);
            if (k - 1 >= 0) cpB(k - 1, a1, c1);
            ldB(k - 3, a1, c1);
        }
    } else {
        // ---- score + chunk3 forward walk: [2G, T) ----
        out_scores[s] = score;
        int tag = b2;                       // state at t = 2G-1
        const int NCu = (T - G2 + 7) >> 3;  // blocks needed to cover p < T
        const uint8_t* cb8 = bpC + (size_t)s * NCpad * 32;
        uint4 a0, c0, a1, c1;
        auto ldC = [&](int k, uint4& qa, uint4& qb) {
            if (k >= NCu) return;
            qa = *(const uint4*)(cb8 + (size_t)k * 32);
            qb = *(const uint4*)(cb8 + (size_t)k * 32 + 16);
        };
        auto cpC = [&](int k, const uint4& qa, const uint4& qb) {
            const uint32_t d[8] = {qa.x, qa.y, qa.z, qa.w, qb.x, qb.y, qb.z, qb.w};
            float buf[8];
#pragma unroll
            for (int j = 0; j < 8; ++j) {
                const int t = G2 - 1 + 8 * k + j;
                const bool act = t < len - 1;   // bb_t valid for t <= len-2
                if (act) { CHASE(j) buf[j] = (float)tag; }
                else buf[j] = 0.0f;
            }
            const int p0 = G2 + 8 * k;          // path index = t+1
            if (p0 + 7 < T) {
                *(float4*)(orow + p0)     = make_float4(buf[0], buf[1], buf[2], buf[3]);
                *(float4*)(orow + p0 + 4) = make_float4(buf[4], buf[5], buf[6], buf[7]);
            } else {
#pragma unroll
                for (int j = 0; j < 8; ++j)
                    if (p0 + j < T) orow[p0 + j] = buf[j];
            }
        };
        int k = 0;
        ldC(0, a0, c0); ldC(1, a1, c1);
        for (; k < NCu; k += 2) {
            cpC(k, a0, c0); ldC(k + 2, a0, c0);
            if (k + 1 < NCu) cpC(k + 1, a1, c1);
            ldC(k + 3, a1, c1);
        }
    }
#undef CHASE
}

// ===========================================================================
// Fallback (ws too small / odd shapes): R8 fused kernel verbatim.
// ===========================================================================
__global__ __launch_bounds__(64, 1) void crf_fused_small(
    const float* __restrict__ feats,
    const int*   __restrict__ lengths,
    const float* __restrict__ trans,
    float*       __restrict__ out_scores,
    float*       __restrict__ out_path,
    uint8_t*     __restrict__ bp4,
    int B, int T)
{
    const int lane = threadIdx.x & 63;
    const int grp  = lane >> 4;
    const int n    = lane & 15;
    const int m    = n & 7;
    const bool odd = (n & 1);
    const int b4   = blockIdx.x * 4;
    const int b    = min(b4 + grp, B - 1);

    const int len = lengths[b];
    const int l0 = lengths[min(b4 + 0, B - 1)];
    const int l1 = lengths[min(b4 + 1, B - 1)];
    const int l2 = lengths[min(b4 + 2, B - 1)];
    const int l3 = lengths[min(b4 + 3, B - 1)];
    const int maxlen = max(max(l0, l1), max(l2, l3));

    int srcv[8];
    srcv[0] = n;
    srcv[1] = DPP_I(n, 0x121);  srcv[2] = DPP_I(n, 0x122);
    srcv[3] = DPP_I(n, 0x123);  srcv[4] = DPP_I(n, 0x124);
    srcv[5] = DPP_I(n, 0x125);  srcv[6] = DPP_I(n, 0x126);
    srcv[7] = DPP_I(n, 0x127);

    float trowR[8];
    int   rsrc[8];
#pragma unroll
    for (int r = 0; r < 8; ++r) {
        const int sq = srcv[r] & 7;
        trowR[r] = trans[m * TAGS + sq];
        rsrc[r]  = sq ^ 7;
    }

    const float* fb = feats + (size_t)b * T * TAGS + m;
    uint8_t* bpb = bp4 + (size_t)b * T * 4 + (n >> 1);
    const bool store_lane = (n < 8) && !odd;

    float fv = trans[m * TAGS + START_TAG] + fb[0];

#define KLEAF_S(r, ctrl) { \
        int rot_ = DPP_I(__float_as_int(fv), (ctrl)); \
        float lv_ = __int_as_float(rot_) + trowR[r]; \
        k##r = __int_as_float((__float_as_int(lv_) & ~7) | rsrc[r]); }

#define STEP_S(TI, FEAT) { \
        const int t_ = (TI); \
        float k0, k1, k2, k3, k4, k5, k6, k7; \
        { float lv_ = fv + trowR[0]; \
          k0 = __int_as_float((__float_as_int(lv_) & ~7) | rsrc[0]); } \
        KLEAF_S(1, 0x121) KLEAF_S(2, 0x122) KLEAF_S(3, 0x123) \
        KLEAF_S(4, 0x124) KLEAF_S(5, 0x125) KLEAF_S(6, 0x126) \
        KLEAF_S(7, 0x127) \
        const float p1_ = maxf3(k0, k1, k2); \
        const float p2_ = maxf3(k3, k4, k5); \
        const float p3_ = maxf3(k6, k7, p1_); \
        const float mm_ = fmaxf(p2_, p3_); \
        const int   idx_  = (__float_as_int(mm_) & 7) ^ 7; \
        const int   pidx_ = DPP_I(idx_, 0xB1); \
        const int   lo_   = odd ? pidx_ : idx_; \
        const int   hi_   = odd ? idx_ : pidx_; \
        const float fvn_  = mm_ + (FEAT); \
        fv = (t_ < len) ? fvn_ : fv; \
        if (t_ < T) { \
            if (store_lane) \
                bpb[(size_t)t_ * 4] = (uint8_t)(lo_ | (hi_ << 4)); \
        } }

    float fc[8], fn[8];
#pragma unroll
    for (int i = 0; i < 8; ++i)
        fc[i] = fb[(size_t)min(1 + i, T - 1) * TAGS];

    for (int t0 = 1; t0 < maxlen; t0 += 8) {
#pragma unroll
        for (int i = 0; i < 8; ++i)
            fn[i] = fb[(size_t)min(t0 + 8 + i, T - 1) * TAGS];

        STEP_S(t0 + 0, fc[0]) STEP_S(t0 + 1, fc[1])
        STEP_S(t0 + 2, fc[2]) STEP_S(t0 + 3, fc[3])
        STEP_S(t0 + 4, fc[4]) STEP_S(t0 + 5, fc[5])
        STEP_S(t0 + 6, fc[6]) STEP_S(t0 + 7, fc[7])

#pragma unroll
        for (int i = 0; i < 8; ++i) fc[i] = fn[i];
    }
#undef KLEAF_S
#undef STEP_S

    const float term = fv + trans[STOP_TAG * TAGS + m];
    float kk = __int_as_float((__float_as_int(term) & ~7) | (m ^ 7));
    kk = fmaxf(kk, __int_as_float(DPP_I(__float_as_int(kk), 0x124)));
    kk = fmaxf(kk, __int_as_float(DPP_I(__float_as_int(kk), 0x122)));
    kk = fmaxf(kk, __int_as_float(DPP_I(__float_as_int(kk), 0x121)));
    int tag = (__float_as_int(kk) & 7) ^ 7;

    if (n == 0)
        out_scores[b] = kk;

    __builtin_amdgcn_s_waitcnt(0);
    __builtin_amdgcn_sched_barrier(0);

    if (n == 0) {
        const uint32_t* rw = (const uint32_t*)(bp4 + (size_t)b * T * 4);
        float* orow = out_path + (size_t)b * T;
        const int NB = (T + 15) / 16;
        uint32_t wA[16], wB[16];

        auto loadblk = [&](int bi, uint32_t* w) {
            if (bi < 0) return;
#pragma unroll
            for (int j = 0; j < 4; ++j) {
                const int tb = min(bi * 16 + 4 * j, T - 4);
                *(uint4*)&w[4 * j] = *(const uint4*)&rw[tb];
            }
        };
        auto compblk = [&](int bi, uint32_t* w) {
            float buf[16];
#pragma unroll
            for (int u = 15; u >= 0; --u) {
                const int t = bi * 16 + u;
                if (t < T) {
                    const bool act = t < len;
                    buf[u] = act ? (float)tag : 0.0f;
                    if (act) tag = (int)((w[u] >> (4 * tag)) & 15);
                }
            }
#pragma unroll
            for (int j = 0; j < 16; j += 4) {
                const int t = bi * 16 + j;
                if (t + 3 < T)
                    *(float4*)(orow + t) = make_float4(buf[j], buf[j+1], buf[j+2], buf[j+3]);
            }
        };

        int bi = NB - 1;
        loadblk(bi, wA);
        loadblk(bi - 1, wB);
        for (; bi >= 0; bi -= 2) {
            compblk(bi, wA);
            loadblk(bi - 2, wA);
            if (bi - 1 >= 0) compblk(bi - 1, wB);
            loadblk(bi - 3, wB);
        }
    }
}

extern "C" void kernel_launch(void* const* d_in, const int* in_sizes, int n_in,
                              void* d_out, int out_size, void* d_ws, size_t ws_size,
                              hipStream_t stream)
{
    const float* feats   = (const float*)d_in[0];
    const int*   lengths = (const int*)d_in[1];
    const float* trans   = (const float*)d_in[2];
    const int B = in_sizes[1];
    const int T = in_sizes[0] / (B * TAGS);

    float* out_scores = (float*)d_out;       // [B]
    float* out_path   = (float*)d_out + B;   // [B, T] tags as floats

    const int G  = ((T / 3) + 15) & ~15;     // chunk size, mult of 16
    const int G2 = 2 * G;
    const int blocksA = (G + 6) >> 3;
    const int blocksB = G >> 3;
    const int NC  = ((T - G2 + 1) + 7) >> 3;
    const int NCpad = ((NC + 2) / 3) * 3;

    const size_t szA = (size_t)B * blocksA * 32;
    const size_t szB = (size_t)B * blocksB * 256;
    const size_t szC = (size_t)B * NCpad * 32;
    const size_t need = szA + szB + szC + (size_t)B * (32 + 256 + 32);

    if (G >= 48 && T > G2 + 2 && (T & 3) == 0 && need <= ws_size) {
        uint8_t* bpA  = (uint8_t*)d_ws;
        uint8_t* bpB  = bpA + szA;
        uint8_t* bpC  = bpB + szB;
        float*   fvAo = (float*)(bpC + szC);
        float*   gws  = fvAo + (size_t)B * 8;
        float*   hws  = gws + (size_t)B * 64;
        const int ABLK = (B + 3) / 4;
        const int CBLK = (B + 3) / 4;

        crf_split3_fwd<<<ABLK + CBLK + B, 64, 0, stream>>>(
            feats, lengths, trans, bpA, bpB, bpC, fvAo, gws, hws,
            B, T, G, ABLK, CBLK, NCpad);

        const int rb = (B + 63) >> 6;
        crf_split3_bt<<<3 * rb, 64, 0, stream>>>(
            lengths, trans, bpA, bpB, bpC, fvAo, gws, hws,
            out_scores, out_path, B, T, G, NCpad);
    } else {
        uint8_t* bp4 = (uint8_t*)d_ws;       // [B][T] 4B words
        crf_fused_small<<<(B + 3) / 4, 64, 0, stream>>>(
            feats, lengths, trans, out_scores, out_path, bp4, B, T);
    }
}

// Round 13
// 117.250 us; speedup vs baseline: 1.9471x; 1.0504x over previous
//
#include <hip/hip_runtime.h>
#include <stdint.h>

#define TAGS 10
#define START_TAG 8
#define STOP_TAG 9
#define NEGV (-10000.0f)
#define BIGNEG (-1.0e9f)

// XOR-r gathers within an 8-lane octet. r=1,2,3: quad_perm DPP; r=7:
// ROW_HALF_MIRROR DPP (lane ^= 7 within octet); r=4,5,6: ds_swizzle BitMode.
#define GX1(x) __builtin_amdgcn_update_dpp(0, (x), 0xB1, 0xF, 0xF, true)
#define GX2(x) __builtin_amdgcn_update_dpp(0, (x), 0x4E, 0xF, 0xF, true)
#define GX3(x) __builtin_amdgcn_update_dpp(0, (x), 0x1B, 0xF, 0xF, true)
#define GX7(x) __builtin_amdgcn_update_dpp(0, (x), 0x141, 0xF, 0xF, true)
#define GX4(x) __builtin_amdgcn_ds_swizzle((x), (4 << 10) | 0x1F)
#define GX5(x) __builtin_amdgcn_ds_swizzle((x), (5 << 10) | 0x1F)
#define GX6(x) __builtin_amdgcn_ds_swizzle((x), (6 << 10) | 0x1F)

__device__ __forceinline__ float maxf3(float a, float b, float c) {
    return fmaxf(fmaxf(a, b), c);   // folds to v_max3_f32
}

// Inline-asm feat loads: structurally pinned (regalloc cannot sink them).
#define GLOADI(dst, base, OFF) \
    asm volatile("global_load_dword %0, %1, off offset:" #OFF \
                 : "=v"(dst) : "v"(base))
#define GLOAD8(BUF, BASE) { \
    const float* gb_ = (BASE); \
    GLOADI(BUF[0], gb_, 0);   GLOADI(BUF[1], gb_, 40); \
    GLOADI(BUF[2], gb_, 80);  GLOADI(BUF[3], gb_, 120); \
    GLOADI(BUF[4], gb_, 160); GLOADI(BUF[5], gb_, 200); \
    GLOADI(BUF[6], gb_, 240); GLOADI(BUF[7], gb_, 280); }
#define GLOAD8X(BUF, FB, TB) { \
    GLOADI(BUF[0], (FB) + (size_t)min((TB) + 0, T - 1) * TAGS, 0); \
    GLOADI(BUF[1], (FB) + (size_t)min((TB) + 1, T - 1) * TAGS, 0); \
    GLOADI(BUF[2], (FB) + (size_t)min((TB) + 2, T - 1) * TAGS, 0); \
    GLOADI(BUF[3], (FB) + (size_t)min((TB) + 3, T - 1) * TAGS, 0); \
    GLOADI(BUF[4], (FB) + (size_t)min((TB) + 4, T - 1) * TAGS, 0); \
    GLOADI(BUF[5], (FB) + (size_t)min((TB) + 5, T - 1) * TAGS, 0); \
    GLOADI(BUF[6], (FB) + (size_t)min((TB) + 6, T - 1) * TAGS, 0); \
    GLOADI(BUF[7], (FB) + (size_t)min((TB) + 7, T - 1) * TAGS, 0); }
// Steady-state exact wait: with one dummy store issued in the prologue the
// newest-17 window is always {cur 8 loads, prev store, prev 8 loads}, so
// vmcnt(17) drains exactly the 2-phase-old buffer (vmcnt(16) over-waited on
// a 1-phase-old load every phase).
#define WAITP { asm volatile("s_waitcnt vmcnt(17)" ::: "memory"); \
                __builtin_amdgcn_sched_barrier(0); }
#define PINFENCE __builtin_amdgcn_sched_barrier(0);

// shared leaf: gather VAL from lane^r, add rotated trans, pack index nibble
#define KLEAF(r, GFN, VAL) { \
        int rot_ = GFN(__float_as_int(VAL)); \
        float lv_ = __int_as_float(rot_) + trowR[r]; \
        k##r = __int_as_float((__float_as_int(lv_) & ~7) | rsrc[r]); }

// ===========================================================================
// K1: 3-chunk forward. [0,ABLK): chunk1 fwd t in [0,G), 8 seqs/wave (octet =
// seq, XOR gathers). [ABLK,ABLK+CBLK): chunk3 BACKWARD t in [2G-1,T), 8 seqs/
// wave. [ABLK+CBLK,+B): chunk2 8-basis t in [G,min(len,2G)), 1 seq/wave.
// bp layout per 8-step block: 32B/seq (chunk1/3) laid [4 byte-pos][8 steps];
// chunk2 256B/block = 8 bases x 32B.
// ===========================================================================
__global__ __launch_bounds__(64, 1) void crf_split3_fwd(
    const float* __restrict__ feats,
    const int*   __restrict__ lengths,
    const float* __restrict__ trans,
    uint8_t*     __restrict__ bpA,
    uint8_t*     __restrict__ bpB,
    uint8_t*     __restrict__ bpC,
    float*       __restrict__ fvAo,
    float*       __restrict__ gws,
    float*       __restrict__ hws,
    int B, int T, int G, int ABLK, int CBLK, int NCpad)
{
    const int lane = threadIdx.x & 63;
    const int G2 = 2 * G;
    const int n = lane & 7;           // tag owned by this lane

    // srcv[r] = source lane (within octet) delivered by gather r — derived by
    // applying the same op to the lane index (convention-proof).
    int srcv[8];
    srcv[0] = n;
    srcv[1] = GX1(lane) & 7;  srcv[2] = GX2(lane) & 7;
    srcv[3] = GX3(lane) & 7;  srcv[4] = GX4(lane) & 7;
    srcv[5] = GX5(lane) & 7;  srcv[6] = GX6(lane) & 7;
    srcv[7] = GX7(lane) & 7;

    int rsrc[8];
#pragma unroll
    for (int r = 0; r < 8; ++r) rsrc[r] = srcv[r] ^ 7;

    if ((int)blockIdx.x < ABLK) {
        // ---------------- chunk 1: forward [0, G), 8 seqs/wave ----------------
        const int oct = lane >> 3;
        const int b8  = blockIdx.x * 8;
        const int b   = min(b8 + oct, B - 1);
        const bool odd = (n & 1);

        const int len  = lengths[b];
        const int lenA = min(len, G);
        int maxlen = 0;
#pragma unroll
        for (int i = 0; i < 8; ++i)
            maxlen = max(maxlen, lengths[min(b8 + i, B - 1)]);
        const int HA = min(maxlen, G);
        const int blocksA = (G + 6) >> 3;

        float trowR[8];
#pragma unroll
        for (int r = 0; r < 8; ++r)
            trowR[r] = trans[n * TAGS + srcv[r]];

        const float* fb = feats + (size_t)b * T * TAGS + n;
        uint8_t* bpa_l = bpA + (size_t)b * blocksA * 32 + (n >> 1) * 8;
        const bool stl = !odd;

        float fv = trans[n * TAGS + START_TAG] + fb[0];

#define STEP_A(TI, FEAT, ACCST) { \
        const int t_ = (TI); \
        float k0, k1, k2, k3, k4, k5, k6, k7; \
        { float lv_ = fv + trowR[0]; \
          k0 = __int_as_float((__float_as_int(lv_) & ~7) | rsrc[0]); } \
        KLEAF(1, GX1, fv) KLEAF(2, GX2, fv) KLEAF(3, GX3, fv) \
        KLEAF(4, GX4, fv) KLEAF(5, GX5, fv) KLEAF(6, GX6, fv) \
        KLEAF(7, GX7, fv) \
        const float p1_ = maxf3(k0, k1, k2); \
        const float p2_ = maxf3(k3, k4, k5); \
        const float p3_ = maxf3(k6, k7, p1_); \
        const float mm_ = fmaxf(p2_, p3_); \
        const int idx_  = (__float_as_int(mm_) & 7) ^ 7; \
        const int pidx_ = GX1(idx_); \
        const uint32_t byte_ = (uint32_t)(odd ? (pidx_ | (idx_ << 4)) \
                                              : (idx_ | (pidx_ << 4))); \
        ACCST; \
        const float fvn_ = mm_ + (FEAT); \
        fv = (t_ < lenA) ? fvn_ : fv; }

#define PH_A(USE, LD, T0) { \
        GLOAD8(LD, fb + (size_t)min((T0) + 16, T - 8) * TAGS); \
        WAITP \
        uint32_t accl, acch; \
        STEP_A((T0) + 0, USE[0], accl = byte_) \
        STEP_A((T0) + 1, USE[1], accl |= byte_ << 8) \
        STEP_A((T0) + 2, USE[2], accl |= byte_ << 16) \
        STEP_A((T0) + 3, USE[3], accl |= byte_ << 24) \
        STEP_A((T0) + 4, USE[4], acch = byte_) \
        STEP_A((T0) + 5, USE[5], acch |= byte_ << 8) \
        STEP_A((T0) + 6, USE[6], acch |= byte_ << 16) \
        STEP_A((T0) + 7, USE[7], acch |= byte_ << 24) \
        if ((T0) < G) { \
            if (stl) *(uint2*)(bpa_l + (size_t)(((T0) - 1) >> 3) * 32) \
                         = make_uint2(accl, acch); } }

        PINFENCE
        float xb[8], yb[8], zb[8];
        GLOAD8(xb, fb + (size_t)1 * TAGS);
        GLOAD8(yb, fb + (size_t)min(9, T - 8) * TAGS);
        *(volatile float*)(fvAo + (size_t)b * 8 + n) = 0.0f;  // vmcnt dummy

        for (int t0 = 1; t0 < HA; t0 += 24) {
            PH_A(xb, zb, t0)
            PH_A(yb, xb, t0 + 8)
            PH_A(zb, yb, t0 + 16)
        }
#undef STEP_A
#undef PH_A

        fvAo[(size_t)b * 8 + n] = fv;        // overwrites dummy (same wave, in order)
    } else if ((int)blockIdx.x < ABLK + CBLK) {
        // ---------------- chunk 3: backward [2G-1, T), 8 seqs/wave ----------------
        const int oct = lane >> 3;
        const int c8  = (blockIdx.x - ABLK) * 8;
        const int b   = min(c8 + oct, B - 1);
        const bool odd = (n & 1);
        const int len  = lengths[b];
        const int lenm1 = len - 1;           // step t active iff t < len-1

        // backward: h_t[n] = max_q (feat_{t+1}[q] + h_{t+1}[q] + trans[q][n])
        float trowR[8];
#pragma unroll
        for (int r = 0; r < 8; ++r)
            trowR[r] = trans[srcv[r] * TAGS + n];

        float h = trans[STOP_TAG * TAGS + n];   // init at t = len-1
        const float* fb = feats + (size_t)b * T * TAGS + n;
        uint8_t* bpc_l = bpC + (size_t)b * NCpad * 32 + (n >> 1) * 8;
        const bool stl = !odd;

#define STEP_C(K, J, FEAT, ACCST) { \
        const int t_ = G2 - 1 + 8 * (K) + (J); \
        const float e_ = h + (FEAT); \
        float k0, k1, k2, k3, k4, k5, k6, k7; \
        { float lv_ = e_ + trowR[0]; \
          k0 = __int_as_float((__float_as_int(lv_) & ~7) | rsrc[0]); } \
        KLEAF(1, GX1, e_) KLEAF(2, GX2, e_) KLEAF(3, GX3, e_) \
        KLEAF(4, GX4, e_) KLEAF(5, GX5, e_) KLEAF(6, GX6, e_) \
        KLEAF(7, GX7, e_) \
        const float p1_ = maxf3(k0, k1, k2); \
        const float p2_ = maxf3(k3, k4, k5); \
        const float p3_ = maxf3(k6, k7, p1_); \
        const float mm_ = fmaxf(p2_, p3_); \
        const int idx_  = (__float_as_int(mm_) & 7) ^ 7; \
        const int pidx_ = GX1(idx_); \
        const uint32_t byte_ = (uint32_t)(odd ? (pidx_ | (idx_ << 4)) \
                                              : (idx_ | (pidx_ << 4))); \
        ACCST; \
        h = (t_ < lenm1) ? mm_ : h; }

#define PH_C(USE, LD, K) { \
        GLOAD8X(LD, fb, G2 + 8 * ((K) - 2)) \
        WAITP \
        uint32_t accl, acch; \
        STEP_C(K, 7, USE[7], acch = byte_ << 24) \
        STEP_C(K, 6, USE[6], acch |= byte_ << 16) \
        STEP_C(K, 5, USE[5], acch |= byte_ << 8) \
        STEP_C(K, 4, USE[4], acch |= byte_) \
        STEP_C(K, 3, USE[3], accl = byte_ << 24) \
        STEP_C(K, 2, USE[2], accl |= byte_ << 16) \
        STEP_C(K, 1, USE[1], accl |= byte_ << 8) \
        STEP_C(K, 0, USE[0], accl |= byte_) \
        if (stl) *(uint2*)(bpc_l + (size_t)(K) * 32) = make_uint2(accl, acch); }

        PINFENCE
        float xb[8], yb[8], zb[8];
        GLOAD8X(xb, fb, G2 + 8 * (NCpad - 1))
        GLOAD8X(yb, fb, G2 + 8 * (NCpad - 2))
        *(volatile float*)(hws + (size_t)b * 8 + n) = 0.0f;   // vmcnt dummy

        for (int k = NCpad - 1; k >= 0; k -= 3) {   // NCpad multiple of 3
            PH_C(xb, zb, k)
            PH_C(yb, xb, k - 1)
            PH_C(zb, yb, k - 2)
        }
#undef STEP_C
#undef PH_C

        hws[(size_t)b * 8 + n] = h;          // h at t = 2G-1
    } else {
        // ---------------- chunk 2: 8-basis [G, min(len,2G)), 1 seq/wave ----------------
        const int s = blockIdx.x - ABLK - CBLK;
        if (s >= B) return;
        const int len = lengths[s];
        if (len <= G) return;
        const int lenB2 = min(len, G2);

        const int p    = lane >> 3;       // basis octet
        const bool odd = (n & 1);
        const int blocksB = G >> 3;

        float trowR[8];
#pragma unroll
        for (int r = 0; r < 8; ++r)
            trowR[r] = trans[n * TAGS + srcv[r]];

        float g = (n == p) ? 0.0f : BIGNEG;   // basis e_p at t = G-1
        const float* fb = feats + (size_t)s * T * TAGS + n;
        uint8_t* bpb_l = bpB + (size_t)s * blocksB * 256 + p * 32 + (n >> 1) * 8;

#define STEP_B(TI, FEAT, ACCST) { \
        const int t_ = (TI); \
        float k0, k1, k2, k3, k4, k5, k6, k7; \
        { float lv_ = g + trowR[0]; \
          k0 = __int_as_float((__float_as_int(lv_) & ~7) | rsrc[0]); } \
        KLEAF(1, GX1, g) KLEAF(2, GX2, g) KLEAF(3, GX3, g) \
        KLEAF(4, GX4, g) KLEAF(5, GX5, g) KLEAF(6, GX6, g) \
        KLEAF(7, GX7, g) \
        const float p1_ = maxf3(k0, k1, k2); \
        const float p2_ = maxf3(k3, k4, k5); \
        const float p3_ = maxf3(k6, k7, p1_); \
        const float mm_ = fmaxf(p2_, p3_); \
        const int idx_  = (__float_as_int(mm_) & 7) ^ 7; \
        const int pidx_ = GX1(idx_); \
        const uint32_t byte_ = (uint32_t)(odd ? (pidx_ | (idx_ << 4)) \
                                              : (idx_ | (pidx_ << 4))); \
        ACCST; \
        g = (t_ < lenB2) ? (mm_ + (FEAT)) : g; }

#define PH_B(USE, LD, T0) { \
        GLOAD8(LD, fb + (size_t)min((T0) + 16, T - 8) * TAGS); \
        WAITP \
        uint32_t accl, acch; \
        STEP_B((T0) + 0, USE[0], accl = byte_) \
        STEP_B((T0) + 1, USE[1], accl |= byte_ << 8) \
        STEP_B((T0) + 2, USE[2], accl |= byte_ << 16) \
        STEP_B((T0) + 3, USE[3], accl |= byte_ << 24) \
        STEP_B((T0) + 4, USE[4], acch = byte_) \
        STEP_B((T0) + 5, USE[5], acch |= byte_ << 8) \
        STEP_B((T0) + 6, USE[6], acch |= byte_ << 16) \
        STEP_B((T0) + 7, USE[7], acch |= byte_ << 24) \
        if ((T0) < G2) { \
            if (!odd) *(uint2*)(bpb_l + (size_t)(((T0) - G) >> 3) * 256) \
                          = make_uint2(accl, acch); } }

        PINFENCE
        float xb[8], yb[8], zb[8];
        GLOAD8(xb, fb + (size_t)G * TAGS);
        GLOAD8(yb, fb + (size_t)min(G + 8, T - 8) * TAGS);
        *(volatile float*)(gws + (size_t)s * 64 + lane) = 0.0f;  // vmcnt dummy

        for (int t0 = G; t0 < lenB2; t0 += 24) {
            PH_B(xb, zb, t0)
            PH_B(yb, xb, t0 + 8)
            PH_B(zb, yb, t0 + 16)
        }
#undef STEP_B
#undef PH_B

        gws[(size_t)s * 64 + lane] = g;   // lane = p*8 + n
    }
}

// ===========================================================================
// Seam composition (unchanged, R12-verified).
// ===========================================================================
__device__ __forceinline__ void crf_compose(
    const float* __restrict__ fv1p, const float* __restrict__ gp,
    const float* __restrict__ hp, const float* __restrict__ trans,
    int len, int G, int G2, float& score, int& b1, int& b2)
{
    float fa[8];
    {
        const float4* f4 = (const float4*)fv1p;
        float4 a = f4[0], c = f4[1];
        fa[0]=a.x; fa[1]=a.y; fa[2]=a.z; fa[3]=a.w;
        fa[4]=c.x; fa[5]=c.y; fa[6]=c.z; fa[7]=c.w;
    }
    const bool hasB = len > G, hasC = len > G2;
    float fv2[8];
    if (hasB) {
#pragma unroll
        for (int nn = 0; nn < 8; ++nn) fv2[nn] = fa[0] + gp[nn];
#pragma unroll
        for (int pp = 1; pp < 8; ++pp)
#pragma unroll
            for (int nn = 0; nn < 8; ++nn)
                fv2[nn] = fmaxf(fv2[nn], fa[pp] + gp[pp * 8 + nn]);
    } else {
#pragma unroll
        for (int nn = 0; nn < 8; ++nn) fv2[nn] = fa[nn];
    }
    float best; int bb = 0;
    if (hasC) {
        best = fv2[0] + hp[0];
#pragma unroll
        for (int nn = 1; nn < 8; ++nn) {
            const float v = fv2[nn] + hp[nn];
            if (v > best) { best = v; bb = nn; }
        }
    } else {
        best = fv2[0] + trans[STOP_TAG * TAGS + 0];
#pragma unroll
        for (int nn = 1; nn < 8; ++nn) {
            const float v = fv2[nn] + trans[STOP_TAG * TAGS + nn];
            if (v > best) { best = v; bb = nn; }
        }
    }
    b2 = bb;
    if (hasB) {
        float bv = fa[0] + gp[bb]; int q0 = 0;
#pragma unroll
        for (int q = 1; q < 8; ++q) {
            const float v = fa[q] + gp[q * 8 + bb];
            if (v > bv) { bv = v; q0 = q; }
        }
        b1 = q0;
    } else {
        b1 = bb;
    }
    score = best;
}

// ===========================================================================
// K2: three backtrace roles per sequence (unchanged, R12-verified).
// ===========================================================================
__global__ __launch_bounds__(64, 1) void crf_split3_bt(
    const int*     __restrict__ lengths,
    const float*   __restrict__ trans,
    const uint8_t* __restrict__ bpA,
    const uint8_t* __restrict__ bpB,
    const uint8_t* __restrict__ bpC,
    const float*   __restrict__ fvA,
    const float*   __restrict__ gws,
    const float*   __restrict__ hws,
    float*         __restrict__ out_scores,
    float*         __restrict__ out_path,
    int B, int T, int G, int NCpad)
{
    const int rb = (B + 63) >> 6;
    const int role = blockIdx.x / rb;
    const int s = (blockIdx.x % rb) * 64 + threadIdx.x;
    if (s >= B) return;
    const int len = lengths[s];
    const int G2 = 2 * G;
    const int blocksA = (G + 6) >> 3;
    const int blocksB = G >> 3;

    float score; int b1, b2;
    crf_compose(fvA + (size_t)s * 8, gws + (size_t)s * 64, hws + (size_t)s * 8,
                trans, len, G, G2, score, b1, b2);

    float* orow = out_path + (size_t)s * T;

#define CHASE(J) { \
        const uint32_t sA_ = (tag & 2) ? d[2 + ((J) >> 2)] : d[((J) >> 2)]; \
        const uint32_t sB_ = (tag & 2) ? d[6 + ((J) >> 2)] : d[4 + ((J) >> 2)]; \
        const uint32_t sel_ = (tag & 4) ? sB_ : sA_; \
        tag = (int)((sel_ >> (8 * ((J) & 3) + 4 * (tag & 1))) & 7); }

    if (role == 0) {
        const int lenA = min(len, G);
        int tag = b1;
        const uint8_t* ab8 = bpA + (size_t)s * blocksA * 32;
        uint4 a0, c0, a1, c1;
        auto ldA = [&](int k, uint4& qa, uint4& qb) {
            if (k < 0) return;
            qa = *(const uint4*)(ab8 + (size_t)k * 32);
            qb = *(const uint4*)(ab8 + (size_t)k * 32 + 16);
        };
        auto cpA = [&](int k, const uint4& qa, const uint4& qb) {
            const uint32_t d[8] = {qa.x, qa.y, qa.z, qa.w, qb.x, qb.y, qb.z, qb.w};
#pragma unroll
            for (int u = 7; u >= 0; --u) {
                const int t = 8 * k + 1 + u;
                if (t < G) {
                    const bool act = t < lenA;
                    orow[t] = act ? (float)tag : 0.0f;
                    if (act) CHASE(u)
                }
            }
        };
        int k = blocksA - 1;
        ldA(k, a0, c0); ldA(k - 1, a1, c1);
        for (; k >= 0; k -= 2) {
            cpA(k, a0, c0); ldA(k - 2, a0, c0);
            if (k - 1 >= 0) cpA(k - 1, a1, c1);
            ldA(k - 3, a1, c1);
        }
        orow[0] = (float)tag;
    } else if (role == 1) {
        const int lenB = min(len, G2);
        int tag = b2;
        const uint8_t* bb8 = bpB + (size_t)s * blocksB * 256 + b1 * 32;
        uint4 a0, c0, a1, c1;
        auto ldB = [&](int k, uint4& qa, uint4& qb) {
            if (k < 0) return;
            qa = *(const uint4*)(bb8 + (size_t)k * 256);
            qb = *(const uint4*)(bb8 + (size_t)k * 256 + 16);
        };
        auto cpB = [&](int k, const uint4& qa, const uint4& qb) {
            const uint32_t d[8] = {qa.x, qa.y, qa.z, qa.w, qb.x, qb.y, qb.z, qb.w};
            float buf[8];
#pragma unroll
            for (int u = 7; u >= 0; --u) {
                const int t = G + 8 * k + u;
                const bool act = t < lenB;
                buf[u] = act ? (float)tag : 0.0f;
                if (act) CHASE(u)
            }
            const int t0 = G + 8 * k;
            *(float4*)(orow + t0)     = make_float4(buf[0], buf[1], buf[2], buf[3]);
            *(float4*)(orow + t0 + 4) = make_float4(buf[4], buf[5], buf[6], buf[7]);
        };
        int k = blocksB - 1;
        ldB(k, a0, c0); ldB(k - 1, a1, c1);
        for (; k >= 0; k -= 2) {
            cpB(k, a0, c0); ldB(k - 2, a0, c0);
            if (k - 1 >= 0) cpB(k - 1, a1, c1);
            ldB(k - 3, a1, c1);
        }
    } else {
        out_scores[s] = score;
        int tag = b2;                       // state at t = 2G-1
        const int NCu = (T - G2 + 7) >> 3;
        const uint8_t* cb8 = bpC + (size_t)s * NCpad * 32;
        uint4 a0, c0, a1, c1;
        auto ldC = [&](int k, uint4& qa, uint4& qb) {
            if (k >= NCu) return;
            qa = *(const uint4*)(cb8 + (size_t)k * 32);
            qb = *(const uint4*)(cb8 + (size_t)k * 32 + 16);
        };
        auto cpC = [&](int k, const uint4& qa, const uint4& qb) {
            const uint32_t d[8] = {qa.x, qa.y, qa.z, qa.w, qb.x, qb.y, qb.z, qb.w};
            float buf[8];
#pragma unroll
            for (int j = 0; j < 8; ++j) {
                const int t = G2 - 1 + 8 * k + j;
                const bool act = t < len - 1;
                if (act) { CHASE(j) buf[j] = (float)tag; }
                else buf[j] = 0.0f;
            }
            const int p0 = G2 + 8 * k;
            if (p0 + 7 < T) {
                *(float4*)(orow + p0)     = make_float4(buf[0], buf[1], buf[2], buf[3]);
                *(float4*)(orow + p0 + 4) = make_float4(buf[4], buf[5], buf[6], buf[7]);
            } else {
#pragma unroll
                for (int j = 0; j < 8; ++j)
                    if (p0 + j < T) orow[p0 + j] = buf[j];
            }
        };
        int k = 0;
        ldC(0, a0, c0); ldC(1, a1, c1);
        for (; k < NCu; k += 2) {
            cpC(k, a0, c0); ldC(k + 2, a0, c0);
            if (k + 1 < NCu) cpC(k + 1, a1, c1);
            ldC(k + 3, a1, c1);
        }
    }
#undef CHASE
}

// ===========================================================================
// Fallback (ws too small / odd shapes): R8 fused kernel verbatim.
// ===========================================================================
#define DPP_I(x, ctrl) __builtin_amdgcn_update_dpp(0, (x), (ctrl), 0xF, 0xF, true)

__global__ __launch_bounds__(64, 1) void crf_fused_small(
    const float* __restrict__ feats,
    const int*   __restrict__ lengths,
    const float* __restrict__ trans,
    float*       __restrict__ out_scores,
    float*       __restrict__ out_path,
    uint8_t*     __restrict__ bp4,
    int B, int T)
{
    const int lane = threadIdx.x & 63;
    const int grp  = lane >> 4;
    const int n    = lane & 15;
    const int m    = n & 7;
    const bool odd = (n & 1);
    const int b4   = blockIdx.x * 4;
    const int b    = min(b4 + grp, B - 1);

    const int len = lengths[b];
    const int l0 = lengths[min(b4 + 0, B - 1)];
    const int l1 = lengths[min(b4 + 1, B - 1)];
    const int l2 = lengths[min(b4 + 2, B - 1)];
    const int l3 = lengths[min(b4 + 3, B - 1)];
    const int maxlen = max(max(l0, l1), max(l2, l3));

    int srcv[8];
    srcv[0] = n;
    srcv[1] = DPP_I(n, 0x121);  srcv[2] = DPP_I(n, 0x122);
    srcv[3] = DPP_I(n, 0x123);  srcv[4] = DPP_I(n, 0x124);
    srcv[5] = DPP_I(n, 0x125);  srcv[6] = DPP_I(n, 0x126);
    srcv[7] = DPP_I(n, 0x127);

    float trowR[8];
    int   rsrc[8];
#pragma unroll
    for (int r = 0; r < 8; ++r) {
        const int sq = srcv[r] & 7;
        trowR[r] = trans[m * TAGS + sq];
        rsrc[r]  = sq ^ 7;
    }

    const float* fb = feats + (size_t)b * T * TAGS + m;
    uint8_t* bpb = bp4 + (size_t)b * T * 4 + (n >> 1);
    const bool store_lane = (n < 8) && !odd;

    float fv = trans[m * TAGS + START_TAG] + fb[0];

#define KLEAF_S(r, ctrl) { \
        int rot_ = DPP_I(__float_as_int(fv), (ctrl)); \
        float lv_ = __int_as_float(rot_) + trowR[r]; \
        k##r = __int_as_float((__float_as_int(lv_) & ~7) | rsrc[r]); }

#define STEP_S(TI, FEAT) { \
        const int t_ = (TI); \
        float k0, k1, k2, k3, k4, k5, k6, k7; \
        { float lv_ = fv + trowR[0]; \
          k0 = __int_as_float((__float_as_int(lv_) & ~7) | rsrc[0]); } \
        KLEAF_S(1, 0x121) KLEAF_S(2, 0x122) KLEAF_S(3, 0x123) \
        KLEAF_S(4, 0x124) KLEAF_S(5, 0x125) KLEAF_S(6, 0x126) \
        KLEAF_S(7, 0x127) \
        const float p1_ = maxf3(k0, k1, k2); \
        const float p2_ = maxf3(k3, k4, k5); \
        const float p3_ = maxf3(k6, k7, p1_); \
        const float mm_ = fmaxf(p2_, p3_); \
        const int   idx_  = (__float_as_int(mm_) & 7) ^ 7; \
        const int   pidx_ = DPP_I(idx_, 0xB1); \
        const int   lo_   = odd ? pidx_ : idx_; \
        const int   hi_   = odd ? idx_ : pidx_; \
        const float fvn_  = mm_ + (FEAT); \
        fv = (t_ < len) ? fvn_ : fv; \
        if (t_ < T) { \
            if (store_lane) \
                bpb[(size_t)t_ * 4] = (uint8_t)(lo_ | (hi_ << 4)); \
        } }

    float fc[8], fn[8];
#pragma unroll
    for (int i = 0; i < 8; ++i)
        fc[i] = fb[(size_t)min(1 + i, T - 1) * TAGS];

    for (int t0 = 1; t0 < maxlen; t0 += 8) {
#pragma unroll
        for (int i = 0; i < 8; ++i)
            fn[i] = fb[(size_t)min(t0 + 8 + i, T - 1) * TAGS];

        STEP_S(t0 + 0, fc[0]) STEP_S(t0 + 1, fc[1])
        STEP_S(t0 + 2, fc[2]) STEP_S(t0 + 3, fc[3])
        STEP_S(t0 + 4, fc[4]) STEP_S(t0 + 5, fc[5])
        STEP_S(t0 + 6, fc[6]) STEP_S(t0 + 7, fc[7])

#pragma unroll
        for (int i = 0; i < 8; ++i) fc[i] = fn[i];
    }
#undef KLEAF_S
#undef STEP_S

    const float term = fv + trans[STOP_TAG * TAGS + m];
    float kk = __int_as_float((__float_as_int(term) & ~7) | (m ^ 7));
    kk = fmaxf(kk, __int_as_float(DPP_I(__float_as_int(kk), 0x124)));
    kk = fmaxf(kk, __int_as_float(DPP_I(__float_as_int(kk), 0x122)));
    kk = fmaxf(kk, __int_as_float(DPP_I(__float_as_int(kk), 0x121)));
    int tag = (__float_as_int(kk) & 7) ^ 7;

    if (n == 0)
        out_scores[b] = kk;

    __builtin_amdgcn_s_waitcnt(0);
    __builtin_amdgcn_sched_barrier(0);

    if (n == 0) {
        const uint32_t* rw = (const uint32_t*)(bp4 + (size_t)b * T * 4);
        float* orow = out_path + (size_t)b * T;
        const int NB = (T + 15) / 16;
        uint32_t wA[16], wB[16];

        auto loadblk = [&](int bi, uint32_t* w) {
            if (bi < 0) return;
#pragma unroll
            for (int j = 0; j < 4; ++j) {
                const int tb = min(bi * 16 + 4 * j, T - 4);
                *(uint4*)&w[4 * j] = *(const uint4*)&rw[tb];
            }
        };
        auto compblk = [&](int bi, uint32_t* w) {
            float buf[16];
#pragma unroll
            for (int u = 15; u >= 0; --u) {
                const int t = bi * 16 + u;
                if (t < T) {
                    const bool act = t < len;
                    buf[u] = act ? (float)tag : 0.0f;
                    if (act) tag = (int)((w[u] >> (4 * tag)) & 15);
                }
            }
#pragma unroll
            for (int j = 0; j < 16; j += 4) {
                const int t = bi * 16 + j;
                if (t + 3 < T)
                    *(float4*)(orow + t) = make_float4(buf[j], buf[j+1], buf[j+2], buf[j+3]);
            }
        };

        int bi = NB - 1;
        loadblk(bi, wA);
        loadblk(bi - 1, wB);
        for (; bi >= 0; bi -= 2) {
            compblk(bi, wA);
            loadblk(bi - 2, wA);
            if (bi - 1 >= 0) compblk(bi - 1, wB);
            loadblk(bi - 3, wB);
        }
    }
}

extern "C" void kernel_launch(void* const* d_in, const int* in_sizes, int n_in,
                              void* d_out, int out_size, void* d_ws, size_t ws_size,
                              hipStream_t stream)
{
    const float* feats   = (const float*)d_in[0];
    const int*   lengths = (const int*)d_in[1];
    const float* trans   = (const float*)d_in[2];
    const int B = in_sizes[1];
    const int T = in_sizes[0] / (B * TAGS);

    float* out_scores = (float*)d_out;       // [B]
    float* out_path   = (float*)d_out + B;   // [B, T] tags as floats

    const int G  = ((T / 3) + 15) & ~15;     // chunk size, mult of 16
    const int G2 = 2 * G;
    const int blocksA = (G + 6) >> 3;
    const int blocksB = G >> 3;
    const int NC  = ((T - G2 + 1) + 7) >> 3;
    const int NCpad = ((NC + 2) / 3) * 3;

    const size_t szA = (size_t)B * blocksA * 32;
    const size_t szB = (size_t)B * blocksB * 256;
    const size_t szC = (size_t)B * NCpad * 32;
    const size_t need = szA + szB + szC + (size_t)B * (32 + 256 + 32);

    if (G >= 48 && T > G2 + 2 && (T & 3) == 0 && need <= ws_size) {
        uint8_t* bpA  = (uint8_t*)d_ws;
        uint8_t* bpB  = bpA + szA;
        uint8_t* bpC  = bpB + szB;
        float*   fvAo = (float*)(bpC + szC);
        float*   gws  = fvAo + (size_t)B * 8;
        float*   hws  = gws + (size_t)B * 64;
        const int ABLK = (B + 7) / 8;
        const int CBLK = (B + 7) / 8;

        crf_split3_fwd<<<ABLK + CBLK + B, 64, 0, stream>>>(
            feats, lengths, trans, bpA, bpB, bpC, fvAo, gws, hws,
            B, T, G, ABLK, CBLK, NCpad);

        const int rb = (B + 63) >> 6;
        crf_split3_bt<<<3 * rb, 64, 0, stream>>>(
            lengths, trans, bpA, bpB, bpC, fvAo, gws, hws,
            out_scores, out_path, B, T, G, NCpad);
    } else {
        uint8_t* bp4 = (uint8_t*)d_ws;       // [B][T] 4B words
        crf_fused_small<<<(B + 3) / 4, 64, 0, stream>>>(
            feats, lengths, trans, out_scores, out_path, bp4, B, T);
    }
}